// Round 1
// baseline (1101.127 us; speedup 1.0000x reference)
//
#include <hip/hip_runtime.h>

#define LAG 5
#define HID 256
#define NA 30
#define NE 870
#define TM 195
#define TT 200
#define NB 2
#define EPN 29   // edges per receiver node (contiguous block e = n*29 + rank(send))
#define EPAD 32

__global__ __launch_bounds__(256) void nri_fused(
    const float* __restrict__ inputs,   // [B,NA,TT]
    const float* __restrict__ mu,       // [B,NE]
    const float* __restrict__ logvar,   // [B,NE]
    const float* __restrict__ eps,      // [B,NE]
    const float* __restrict__ w_msg1,   // [2*LAG, HID]
    const float* __restrict__ b_msg1,   // [HID]
    const float* __restrict__ w_msg2,   // [HID, HID]
    const float* __restrict__ b_msg2,   // [HID]
    const float* __restrict__ w_out1,   // [LAG+HID, HID]
    const float* __restrict__ b_out1,   // [HID]
    const float* __restrict__ w_out2,   // [HID, HID]
    const float* __restrict__ b_out2,   // [HID]
    const float* __restrict__ w_out3,   // [HID, 1]
    const float* __restrict__ b_out3,   // [1]
    float* __restrict__ out)            // [B,NA,TM]
{
    __shared__ float feat[NA][LAG];        // lag-window node features at time t
    __shared__ float edgeval[EPAD];        // reparametrized edge scalars (pad=0)
    __shared__ float hid1s[EPAD][HID];     // msg hidden-1, [edge][channel] (32 KB)
    __shared__ float aug[LAG + HID];       // node MLP input
    __shared__ float o1s[HID];
    __shared__ float red[4];

    const int flat = blockIdx.x;
    const int n = flat % NA;               // receiver node
    const int t = (flat / NA) % TM;
    const int b = flat / (NA * TM);
    const int h = threadIdx.x;             // channel index 0..255

    // ---- stage features + edge scalars ----
    if (h < NA * LAG) {
        int j = h / LAG, l = h % LAG;
        feat[j][l] = inputs[(b * NA + j) * TT + t + l];
    }
    if (h < EPAD) {
        float ev = 0.f;
        if (h < EPN) {
            int e = b * NE + n * EPN + h;
            ev = eps[e] * __expf(0.5f * logvar[e]) + mu[e];
        }
        edgeval[h] = ev;
    }
    __syncthreads();

    // ---- phase 1: hid1 = relu(pre_msg @ W1 + b1) for the 29 incoming edges ----
    float w1r[2 * LAG];
    #pragma unroll
    for (int k = 0; k < 2 * LAG; ++k) w1r[k] = w_msg1[k * HID + h];
    const float bm1 = b_msg1[h];
    float rf[LAG];
    #pragma unroll
    for (int l = 0; l < LAG; ++l) rf[l] = feat[n][l];

    for (int ei = 0; ei < EPN; ++ei) {
        int j = (ei < n) ? ei : ei + 1;   // sender node
        float acc = bm1;
        #pragma unroll
        for (int l = 0; l < LAG; ++l) acc = fmaf(feat[j][l], w1r[l], acc);       // senders first
        #pragma unroll
        for (int l = 0; l < LAG; ++l) acc = fmaf(rf[l], w1r[LAG + l], acc);      // then receivers
        hid1s[ei][h] = fmaxf(acc, 0.f);    // conflict-free write (stride-1 in h)
    }
    #pragma unroll
    for (int ei = EPN; ei < EPAD; ++ei) hid1s[ei][h] = 0.f;
    __syncthreads();

    // ---- phase 2: hid2 = relu(hid1 @ W2 + b2); agg over edges with relu*edge ----
    float acc2[EPAD];
    #pragma unroll
    for (int e = 0; e < EPAD; ++e) acc2[e] = 0.f;

    for (int k = 0; k < HID; k += 4) {
        float w0 = w_msg2[(k + 0) * HID + h];
        float w1 = w_msg2[(k + 1) * HID + h];
        float w2 = w_msg2[(k + 2) * HID + h];
        float w3 = w_msg2[(k + 3) * HID + h];
        #pragma unroll
        for (int e = 0; e < EPAD; ++e) {
            float4 v = *(const float4*)&hid1s[e][k];   // broadcast read, conflict-free
            acc2[e] = fmaf(v.x, w0, acc2[e]);
            acc2[e] = fmaf(v.y, w1, acc2[e]);
            acc2[e] = fmaf(v.z, w2, acc2[e]);
            acc2[e] = fmaf(v.w, w3, acc2[e]);
        }
    }
    const float bm2 = b_msg2[h];
    float agg = 0.f;
    #pragma unroll
    for (int e = 0; e < EPAD; ++e)
        agg = fmaf(fmaxf(acc2[e] + bm2, 0.f), edgeval[e], agg);  // pad edges have edgeval 0

    if (h < LAG) aug[h] = rf[h];
    aug[LAG + h] = agg;
    __syncthreads();

    // ---- phase 3: node MLP 261 -> 256 -> 256 -> 1 ----
    float acc = b_out1[h];
    for (int k = 0; k < LAG + HID; ++k)
        acc = fmaf(aug[k], w_out1[k * HID + h], acc);
    o1s[h] = fmaxf(acc, 0.f);
    __syncthreads();

    acc = b_out2[h];
    for (int k = 0; k < HID; ++k)
        acc = fmaf(o1s[k], w_out2[k * HID + h], acc);
    float o2 = fmaxf(acc, 0.f);

    float v = o2 * w_out3[h];
    #pragma unroll
    for (int off = 32; off > 0; off >>= 1)
        v += __shfl_down(v, off, 64);
    if ((h & 63) == 0) red[h >> 6] = v;
    __syncthreads();
    if (h == 0)
        out[(b * NA + n) * TM + t] = red[0] + red[1] + red[2] + red[3] + b_out3[0];
}

extern "C" void kernel_launch(void* const* d_in, const int* in_sizes, int n_in,
                              void* d_out, int out_size, void* d_ws, size_t ws_size,
                              hipStream_t stream) {
    const float* inputs  = (const float*)d_in[0];
    const float* mu      = (const float*)d_in[1];
    const float* logvar  = (const float*)d_in[2];
    const float* eps     = (const float*)d_in[3];
    // d_in[4] rel_rec, d_in[5] rel_send: graph structure hardcoded (fully connected, no self-loops)
    const float* w_msg1  = (const float*)d_in[6];
    const float* b_msg1  = (const float*)d_in[7];
    const float* w_msg2  = (const float*)d_in[8];
    const float* b_msg2  = (const float*)d_in[9];
    const float* w_out1  = (const float*)d_in[10];
    const float* b_out1  = (const float*)d_in[11];
    const float* w_out2  = (const float*)d_in[12];
    const float* b_out2  = (const float*)d_in[13];
    const float* w_out3  = (const float*)d_in[14];
    const float* b_out3  = (const float*)d_in[15];
    float* out = (float*)d_out;

    dim3 grid(NB * TM * NA);   // 11700 blocks: one per (b, t, receiver node)
    dim3 block(256);
    hipLaunchKernelGGL(nri_fused, grid, block, 0, stream,
                       inputs, mu, logvar, eps,
                       w_msg1, b_msg1, w_msg2, b_msg2,
                       w_out1, b_out1, w_out2, b_out2, w_out3, b_out3,
                       out);
}

// Round 3
// 230.268 us; speedup vs baseline: 4.7819x; 4.7819x over previous
//
#include <hip/hip_runtime.h>

#define LAG 5
#define HID 256
#define NA 30
#define NE 870
#define TM 195
#define TT 200
#define NB 2
#define EPN 29
#define NTB 98                 // ceil(195/2) time-tiles of 2
#define NROWS (NB * TM * NA)   // 11700 (b,t,n) rows
#define APAD 8
#define WPAD 8
#define KC 32                  // K-chunk (1 MFMA k-step)

typedef __bf16 bf16;
typedef __bf16 bf16x8 __attribute__((ext_vector_type(8)));
typedef float floatx4 __attribute__((ext_vector_type(4)));

// ---------------------------------------------------------------- K1: prep
// blocks [0,11700): u,v ; [11700,11956): W2^T ; [11956,12244): W_out1'^T (K=288 padded) ; [12244,12500): W_out2^T
__global__ __launch_bounds__(256) void k1_prep(
    const float* __restrict__ inputs, const float* __restrict__ w_msg1,
    const float* __restrict__ b_msg1, const float* __restrict__ w_msg2,
    const float* __restrict__ w_out1, const float* __restrict__ w_out2,
    bf16* __restrict__ u, bf16* __restrict__ v, bf16* __restrict__ w2t,
    bf16* __restrict__ w1ot, bf16* __restrict__ w2ot)
{
    const int bid = blockIdx.x, tid = threadIdx.x;
    if (bid < NROWS) {
        const int n = bid % NA, t = (bid / NA) % TM, b = bid / (NA * TM);
        const float* ip = inputs + (b * NA + n) * TT + t;
        const float f0 = ip[0], f1 = ip[1], f2 = ip[2], f3 = ip[3], f4 = ip[4];
        float ua = b_msg1[tid];                    // fold b_msg1 into u (sender part)
        ua = fmaf(f0, w_msg1[0 * HID + tid], ua);
        ua = fmaf(f1, w_msg1[1 * HID + tid], ua);
        ua = fmaf(f2, w_msg1[2 * HID + tid], ua);
        ua = fmaf(f3, w_msg1[3 * HID + tid], ua);
        ua = fmaf(f4, w_msg1[4 * HID + tid], ua);
        float va = 0.f;
        va = fmaf(f0, w_msg1[5 * HID + tid], va);
        va = fmaf(f1, w_msg1[6 * HID + tid], va);
        va = fmaf(f2, w_msg1[7 * HID + tid], va);
        va = fmaf(f3, w_msg1[8 * HID + tid], va);
        va = fmaf(f4, w_msg1[9 * HID + tid], va);
        const int idx = (bid << 8) + tid;          // ((b*TM+t)*NA+n)*256 + h
        u[idx] = (bf16)ua;
        v[idx] = (bf16)va;
    } else if (bid < NROWS + 256) {
        const int i = ((bid - NROWS) << 8) + tid;
        const int nn = i >> 8, k = i & 255;
        w2t[i] = (bf16)w_msg2[k * HID + nn];
    } else if (bid < NROWS + 256 + 288) {
        const int i = ((bid - (NROWS + 256)) << 8) + tid;   // [0, 73728)
        const int nn = i / 288, k = i - nn * 288;
        float val;
        if (k < 256)      val = w_out1[(5 + k) * HID + nn];   // agg part (w_out1 rows 5..260)
        else if (k < 261) val = w_out1[(k - 256) * HID + nn]; // feat part (rows 0..4)
        else              val = 0.f;                          // K-pad
        w1ot[i] = (bf16)val;
    } else {
        const int i = ((bid - (NROWS + 256 + 288)) << 8) + tid;
        const int nn = i >> 8, k = i & 255;
        w2ot[i] = (bf16)w_out2[k * HID + nn];
    }
}

// ---------------------------------------------------------------- K2: msg MLP + edge-weighted aggregation
// block per (b, n, t-tile of 2). M=64 rows (2t x 32 edge-slots), N=256, K=256.
__global__ __launch_bounds__(256) void k2_msg(
    const bf16* __restrict__ u, const bf16* __restrict__ v,
    const bf16* __restrict__ w2t,
    const float* __restrict__ mu, const float* __restrict__ logvar,
    const float* __restrict__ eps, const float* __restrict__ b_msg2,
    bf16* __restrict__ agg)
{
    __shared__ bf16 a_lds[64][HID + APAD];     // 33792 B, row stride 528 B
    __shared__ bf16 wlds[HID][KC + WPAD];      // 20480 B, row stride 80 B
    __shared__ float ev_lds[32];

    const int bid = blockIdx.x;
    const int n  = bid % NA;                   // n fastest: consecutive blocks share u rows in L2
    const int tb = (bid / NA) % NTB;
    const int b  = bid / (NA * NTB);
    const int t0 = tb * 2;
    const int tid = threadIdx.x;
    const int lane = tid & 63, w = tid >> 6;
    const int q = lane >> 4, m15 = lane & 15;
    const int wbase = w * 64;

    if (tid < 32) {
        float evv = 0.f;
        if (tid < EPN) {
            const int e = b * NE + n * EPN + tid;
            evv = eps[e] * __expf(0.5f * logvar[e]) + mu[e];
        }
        ev_lds[tid] = evv;
    }

    // ---- stage A = relu(u[send] + v[recv]) : 64 rows x 256 k, 16B chunks ----
    #pragma unroll
    for (int i = 0; i < 8; ++i) {
        const int task = i * 256 + tid;
        const int row = task >> 5, c = task & 31;
        const int tt = row >> 5, ei = row & 31;
        bf16x8 out8;
        if (ei < EPN) {
            int t = t0 + tt; if (t > TM - 1) t = TM - 1;     // clamp (store guarded later)
            const int j = ei + (ei >= n);
            const bf16* up = u + ((((b * TM + t) * NA + j) << 8) + c * 8);
            const bf16* vp = v + ((((b * TM + t) * NA + n) << 8) + c * 8);
            const bf16x8 uu = *(const bf16x8*)up;
            const bf16x8 vv = *(const bf16x8*)vp;
            #pragma unroll
            for (int x = 0; x < 8; ++x)
                out8[x] = (bf16)fmaxf((float)uu[x] + (float)vv[x], 0.f);
        } else {
            #pragma unroll
            for (int x = 0; x < 8; ++x) out8[x] = (bf16)0.f;  // zero pad rows
        }
        *(bf16x8*)&a_lds[row][c * 8] = out8;
    }

    floatx4 acc[4][4];
    #pragma unroll
    for (int mt = 0; mt < 4; ++mt)
        #pragma unroll
        for (int nt = 0; nt < 4; ++nt)
            acc[mt][nt] = (floatx4){0.f, 0.f, 0.f, 0.f};

    for (int kc = 0; kc < 8; ++kc) {
        __syncthreads();                                       // prev chunk consumed / A staged
        #pragma unroll
        for (int i = 0; i < 4; ++i) {                          // stage W2^T[:, kc*32 .. +32)
            const int task = i * 256 + tid;
            const int nn = task >> 2, cc = task & 3;
            *(bf16x8*)&wlds[nn][cc * 8] =
                *(const bf16x8*)&w2t[nn * HID + kc * KC + cc * 8];
        }
        __syncthreads();
        bf16x8 af[4];
        #pragma unroll
        for (int mt = 0; mt < 4; ++mt)
            af[mt] = *(const bf16x8*)&a_lds[mt * 16 + m15][kc * KC + q * 8];
        #pragma unroll
        for (int nt = 0; nt < 4; ++nt) {
            const bf16x8 bfr = *(const bf16x8*)&wlds[wbase + nt * 16 + m15][q * 8];
            #pragma unroll
            for (int mt = 0; mt < 4; ++mt)
                acc[mt][nt] = __builtin_amdgcn_mfma_f32_16x16x32_bf16(af[mt], bfr, acc[mt][nt], 0, 0, 0);
        }
    }

    // ---- epilogue: msg = relu(acc + b2) * edgeval ; sum edges -> agg[b,t,n,:] ----
    float b2v[4];
    #pragma unroll
    for (int nt = 0; nt < 4; ++nt) b2v[nt] = b_msg2[wbase + nt * 16 + m15];

    #pragma unroll
    for (int tt = 0; tt < 2; ++tt) {
        const int t = t0 + tt;
        #pragma unroll
        for (int nt = 0; nt < 4; ++nt) {
            float part = 0.f;
            #pragma unroll
            for (int ml = 0; ml < 2; ++ml) {
                const int mt = tt * 2 + ml;
                #pragma unroll
                for (int reg = 0; reg < 4; ++reg) {
                    const int ei = (ml * 16 + q * 4 + reg);    // row&31; C-layout row = q*4+reg
                    part += ev_lds[ei] * fmaxf(acc[mt][nt][reg] + b2v[nt], 0.f);
                }
            }
            part += __shfl_xor(part, 16, 64);
            part += __shfl_xor(part, 32, 64);
            if (q == 0 && t < TM)
                agg[((((b * TM + t) * NA + n) << 8) + wbase + nt * 16 + m15)] = (bf16)part;
        }
    }
}

// ---------------------------------------------------------------- K3: out MLP 288->256->256->1
// block per 64 (b,t,n) rows.
__global__ __launch_bounds__(256) void k3_out(
    const bf16* __restrict__ agg, const float* __restrict__ inputs,
    const bf16* __restrict__ w1ot, const bf16* __restrict__ w2ot,
    const float* __restrict__ b_out1, const float* __restrict__ b_out2,
    const float* __restrict__ w_out3, const float* __restrict__ b_out3,
    float* __restrict__ out)
{
    __shared__ bf16 a1[64][288 + APAD];        // 37888 B; reused (k<256) as layer-2 activations
    __shared__ bf16 wlds[HID][KC + WPAD];      // 20480 B
    __shared__ float red[256];

    const int R0 = blockIdx.x * 64;
    const int tid = threadIdx.x;
    const int lane = tid & 63, w = tid >> 6;
    const int q = lane >> 4, m15 = lane & 15;
    const int wbase = w * 64;

    // ---- stage A1 = [agg(256) | feat(5) | 0...] ----
    #pragma unroll
    for (int i = 0; i < 8; ++i) {
        const int task = i * 256 + tid;
        const int row = task >> 5, c = task & 31;
        const int R = R0 + row;
        bf16x8 val;
        if (R < NROWS) {
            val = *(const bf16x8*)&agg[(R << 8) + c * 8];
        } else {
            for (int x = 0; x < 8; ++x) val[x] = (bf16)0.f;
        }
        *(bf16x8*)&a1[row][c * 8] = val;
    }
    if (tid < 64) {
        const int R = R0 + tid;
        if (R < NROWS) {
            const int b = R / (TM * NA), rem = R - b * (TM * NA);
            const int t = rem / NA, n = rem - (rem / NA) * NA;
            const float* ip = inputs + (b * NA + n) * TT + t;
            #pragma unroll
            for (int l = 0; l < LAG; ++l) a1[tid][256 + l] = (bf16)ip[l];
            #pragma unroll
            for (int k = 261; k < 288; ++k) a1[tid][k] = (bf16)0.f;
        } else {
            for (int k = 256; k < 288; ++k) a1[tid][k] = (bf16)0.f;
        }
    }

    floatx4 acc[4][4];
    #pragma unroll
    for (int mt = 0; mt < 4; ++mt)
        #pragma unroll
        for (int nt = 0; nt < 4; ++nt)
            acc[mt][nt] = (floatx4){0.f, 0.f, 0.f, 0.f};

    // ---- GEMM1: K=288 (9 chunks) ----
    for (int kc = 0; kc < 9; ++kc) {
        __syncthreads();
        #pragma unroll
        for (int i = 0; i < 4; ++i) {
            const int task = i * 256 + tid;
            const int nn = task >> 2, cc = task & 3;
            *(bf16x8*)&wlds[nn][cc * 8] =
                *(const bf16x8*)&w1ot[nn * 288 + kc * KC + cc * 8];
        }
        __syncthreads();
        bf16x8 af[4];
        #pragma unroll
        for (int mt = 0; mt < 4; ++mt)
            af[mt] = *(const bf16x8*)&a1[mt * 16 + m15][kc * KC + q * 8];
        #pragma unroll
        for (int nt = 0; nt < 4; ++nt) {
            const bf16x8 bfr = *(const bf16x8*)&wlds[wbase + nt * 16 + m15][q * 8];
            #pragma unroll
            for (int mt = 0; mt < 4; ++mt)
                acc[mt][nt] = __builtin_amdgcn_mfma_f32_16x16x32_bf16(af[mt], bfr, acc[mt][nt], 0, 0, 0);
        }
    }
    __syncthreads();   // all GEMM1 reads of a1 done before overwrite

    // ---- epilogue1: out1 = relu(acc + b_out1) -> a1[:, 0:256] (bf16) ----
    {
        float b1v[4];
        #pragma unroll
        for (int nt = 0; nt < 4; ++nt) b1v[nt] = b_out1[wbase + nt * 16 + m15];
        #pragma unroll
        for (int mt = 0; mt < 4; ++mt)
            #pragma unroll
            for (int nt = 0; nt < 4; ++nt)
                #pragma unroll
                for (int reg = 0; reg < 4; ++reg)
                    a1[mt * 16 + q * 4 + reg][wbase + nt * 16 + m15] =
                        (bf16)fmaxf(acc[mt][nt][reg] + b1v[nt], 0.f);
    }

    #pragma unroll
    for (int mt = 0; mt < 4; ++mt)
        #pragma unroll
        for (int nt = 0; nt < 4; ++nt)
            acc[mt][nt] = (floatx4){0.f, 0.f, 0.f, 0.f};

    // ---- GEMM2: K=256 (8 chunks) ----
    for (int kc = 0; kc < 8; ++kc) {
        __syncthreads();
        #pragma unroll
        for (int i = 0; i < 4; ++i) {
            const int task = i * 256 + tid;
            const int nn = task >> 2, cc = task & 3;
            *(bf16x8*)&wlds[nn][cc * 8] =
                *(const bf16x8*)&w2ot[nn * HID + kc * KC + cc * 8];
        }
        __syncthreads();
        bf16x8 af[4];
        #pragma unroll
        for (int mt = 0; mt < 4; ++mt)
            af[mt] = *(const bf16x8*)&a1[mt * 16 + m15][kc * KC + q * 8];
        #pragma unroll
        for (int nt = 0; nt < 4; ++nt) {
            const bf16x8 bfr = *(const bf16x8*)&wlds[wbase + nt * 16 + m15][q * 8];
            #pragma unroll
            for (int mt = 0; mt < 4; ++mt)
                acc[mt][nt] = __builtin_amdgcn_mfma_f32_16x16x32_bf16(af[mt], bfr, acc[mt][nt], 0, 0, 0);
        }
    }

    // ---- epilogue2: relu(+b_out2), dot with w_out3, reduce over 256 cols ----
    {
        float b2v[4], w3v[4];
        #pragma unroll
        for (int nt = 0; nt < 4; ++nt) {
            const int col = wbase + nt * 16 + m15;
            b2v[nt] = b_out2[col];
            w3v[nt] = w_out3[col];
        }
        #pragma unroll
        for (int mt = 0; mt < 4; ++mt)
            #pragma unroll
            for (int reg = 0; reg < 4; ++reg) {
                float p = 0.f;
                #pragma unroll
                for (int nt = 0; nt < 4; ++nt)
                    p += fmaxf(acc[mt][nt][reg] + b2v[nt], 0.f) * w3v[nt];
                p += __shfl_xor(p, 1, 64);
                p += __shfl_xor(p, 2, 64);
                p += __shfl_xor(p, 4, 64);
                p += __shfl_xor(p, 8, 64);
                if (m15 == 0) red[w * 64 + mt * 16 + q * 4 + reg] = p;
            }
    }
    __syncthreads();
    if (tid < 64) {
        const int R = R0 + tid;
        if (R < NROWS) {
            const float val = red[tid] + red[64 + tid] + red[128 + tid] + red[192 + tid] + b_out3[0];
            const int b = R / (TM * NA), rem = R - b * (TM * NA);
            const int t = rem / NA, n = rem - (rem / NA) * NA;
            out[(b * NA + n) * TM + t] = val;
        }
    }
}

// ----------------------------------------------------------------
extern "C" void kernel_launch(void* const* d_in, const int* in_sizes, int n_in,
                              void* d_out, int out_size, void* d_ws, size_t ws_size,
                              hipStream_t stream) {
    const float* inputs  = (const float*)d_in[0];
    const float* mu      = (const float*)d_in[1];
    const float* logvar  = (const float*)d_in[2];
    const float* eps     = (const float*)d_in[3];
    const float* w_msg1  = (const float*)d_in[6];
    const float* b_msg1  = (const float*)d_in[7];
    const float* w_msg2  = (const float*)d_in[8];
    const float* b_msg2  = (const float*)d_in[9];
    const float* w_out1  = (const float*)d_in[10];
    const float* b_out1  = (const float*)d_in[11];
    const float* w_out2  = (const float*)d_in[12];
    const float* b_out2  = (const float*)d_in[13];
    const float* w_out3  = (const float*)d_in[14];
    const float* b_out3  = (const float*)d_in[15];
    float* out = (float*)d_out;

    // workspace layout (bf16 elems): u, v, agg = 11700*256 each; W2^T; W_out1'^T (256x288); W_out2^T
    bf16* u    = (bf16*)d_ws;
    bf16* v    = u    + NROWS * HID;
    bf16* aggw = v    + NROWS * HID;
    bf16* w2t  = aggw + NROWS * HID;
    bf16* w1ot = w2t  + HID * HID;
    bf16* w2ot = w1ot + HID * 288;   // total ~18.4 MB

    hipLaunchKernelGGL(k1_prep, dim3(NROWS + 256 + 288 + 256), dim3(256), 0, stream,
                       inputs, w_msg1, b_msg1, w_msg2, w_out1, w_out2,
                       u, v, w2t, w1ot, w2ot);
    hipLaunchKernelGGL(k2_msg, dim3(NB * NA * NTB), dim3(256), 0, stream,
                       u, v, w2t, mu, logvar, eps, b_msg2, aggw);
    hipLaunchKernelGGL(k3_out, dim3((NROWS + 63) / 64), dim3(256), 0, stream,
                       aggw, inputs, w1ot, w2ot, b_out1, b_out2, w_out3, b_out3, out);
}

// Round 4
// 223.096 us; speedup vs baseline: 4.9357x; 1.0321x over previous
//
#include <hip/hip_runtime.h>

#define LAG 5
#define HID 256
#define NA 30
#define NE 870
#define TM 195
#define TT 200
#define NB 2
#define EPN 29
#define NTB 98                 // ceil(195/2) time-tiles of 2
#define NROWS (NB * TM * NA)   // 11700 (b,t,n) rows
#define APAD 8
#define KC 32                  // K-chunk (1 MFMA k-step)
#define K1UV (NB * TM)         // 390 u,v blocks in k1

typedef __bf16 bf16;
typedef __bf16 bf16x8 __attribute__((ext_vector_type(8)));
typedef float floatx4 __attribute__((ext_vector_type(4)));

// ---------------------------------------------------------------- K1: prep
// blocks [0,390): u,v per (b,t) over all 30 nodes
// [390,646): W2^T ; [646,934): W_out1'^T (K=288 padded) ; [934,1190): W_out2^T
__global__ __launch_bounds__(256) void k1_prep(
    const float* __restrict__ inputs, const float* __restrict__ w_msg1,
    const float* __restrict__ b_msg1, const float* __restrict__ w_msg2,
    const float* __restrict__ w_out1, const float* __restrict__ w_out2,
    bf16* __restrict__ u, bf16* __restrict__ v, bf16* __restrict__ w2t,
    bf16* __restrict__ w1ot, bf16* __restrict__ w2ot)
{
    __shared__ float feats[NA][LAG];
    const int bid = blockIdx.x, tid = threadIdx.x;
    if (bid < K1UV) {
        const int b = bid / TM, t = bid % TM;
        if (tid < NA * LAG) {
            const int n = tid / LAG, l = tid % LAG;
            feats[n][l] = inputs[(b * NA + n) * TT + t + l];
        }
        __syncthreads();
        float w1c[2 * LAG];
        #pragma unroll
        for (int k = 0; k < 2 * LAG; ++k) w1c[k] = w_msg1[k * HID + tid];
        const float bb = b_msg1[tid];
        for (int n = 0; n < NA; ++n) {
            float ua = bb, va = 0.f;
            #pragma unroll
            for (int l = 0; l < LAG; ++l) {
                ua = fmaf(feats[n][l], w1c[l], ua);
                va = fmaf(feats[n][l], w1c[LAG + l], va);
            }
            const int idx = (((b * TM + t) * NA + n) << 8) + tid;
            u[idx] = (bf16)ua;
            v[idx] = (bf16)va;
        }
    } else if (bid < K1UV + 256) {
        const int i = ((bid - K1UV) << 8) + tid;
        const int nn = i >> 8, k = i & 255;
        w2t[i] = (bf16)w_msg2[k * HID + nn];
    } else if (bid < K1UV + 256 + 288) {
        const int i = ((bid - (K1UV + 256)) << 8) + tid;   // [0, 73728)
        const int nn = i / 288, k = i - nn * 288;
        float val;
        if (k < 256)      val = w_out1[(5 + k) * HID + nn];   // agg part (rows 5..260)
        else if (k < 261) val = w_out1[(k - 256) * HID + nn]; // feat part (rows 0..4)
        else              val = 0.f;                          // K-pad
        w1ot[i] = (bf16)val;
    } else {
        const int i = ((bid - (K1UV + 256 + 288)) << 8) + tid;
        const int nn = i >> 8, k = i & 255;
        w2ot[i] = (bf16)w_out2[k * HID + nn];
    }
}

// ---------------------------------------------------------------- K2: msg MLP + edge-weighted aggregation
// block per (b, n, t-tile of 2). M=64 rows (2t x 32 edge-slots), N=256, K=256.
// B-operand (W2^T) goes global->register directly (B-frag layout), double-buffered:
// NO barriers in the K-loop.
__global__ __launch_bounds__(256) void k2_msg(
    const bf16* __restrict__ u, const bf16* __restrict__ v,
    const bf16* __restrict__ w2t,
    const float* __restrict__ mu, const float* __restrict__ logvar,
    const float* __restrict__ eps, const float* __restrict__ b_msg2,
    bf16* __restrict__ agg)
{
    __shared__ bf16 a_lds[64][HID + APAD];     // 33792 B
    __shared__ float ev_lds[32];

    const int bid = blockIdx.x;
    const int n  = bid % NA;
    const int tb = (bid / NA) % NTB;
    const int b  = bid / (NA * NTB);
    const int t0 = tb * 2;
    const int tid = threadIdx.x;
    const int lane = tid & 63, w = tid >> 6;
    const int q = lane >> 4, m15 = lane & 15;
    const int wbase = w * 64;

    if (tid < 32) {
        float evv = 0.f;
        if (tid < EPN) {
            const int e = b * NE + n * EPN + tid;
            evv = eps[e] * __expf(0.5f * logvar[e]) + mu[e];
        }
        ev_lds[tid] = evv;
    }

    // ---- stage A = relu(u[send] + v[recv]) : 64 rows x 256 k ----
    #pragma unroll
    for (int i = 0; i < 8; ++i) {
        const int task = i * 256 + tid;
        const int row = task >> 5, c = task & 31;
        const int tt = row >> 5, ei = row & 31;
        bf16x8 out8;
        if (ei < EPN) {
            int t = t0 + tt; if (t > TM - 1) t = TM - 1;     // clamp (store guarded later)
            const int j = ei + (ei >= n);
            const bf16* up = u + ((((b * TM + t) * NA + j) << 8) + c * 8);
            const bf16* vp = v + ((((b * TM + t) * NA + n) << 8) + c * 8);
            const bf16x8 uu = *(const bf16x8*)up;
            const bf16x8 vv = *(const bf16x8*)vp;
            #pragma unroll
            for (int x = 0; x < 8; ++x)
                out8[x] = (bf16)fmaxf((float)uu[x] + (float)vv[x], 0.f);
        } else {
            #pragma unroll
            for (int x = 0; x < 8; ++x) out8[x] = (bf16)0.f;  // zero pad rows
        }
        *(bf16x8*)&a_lds[row][c * 8] = out8;
    }

    // B-frag base pointers: lane (n-col = wbase+nt*16+m15) reads 8 contiguous k
    const bf16* bptr[4];
    #pragma unroll
    for (int nt = 0; nt < 4; ++nt)
        bptr[nt] = w2t + (wbase + nt * 16 + m15) * HID + q * 8;

    bf16x8 bcur[4], bnxt[4];
    #pragma unroll
    for (int nt = 0; nt < 4; ++nt) bcur[nt] = *(const bf16x8*)bptr[nt];

    floatx4 acc[4][4];
    #pragma unroll
    for (int mt = 0; mt < 4; ++mt)
        #pragma unroll
        for (int nt = 0; nt < 4; ++nt)
            acc[mt][nt] = (floatx4){0.f, 0.f, 0.f, 0.f};

    __syncthreads();   // A staged (the only barrier)

    #pragma unroll
    for (int kc = 0; kc < 8; ++kc) {
        if (kc < 7) {
            #pragma unroll
            for (int nt = 0; nt < 4; ++nt)
                bnxt[nt] = *(const bf16x8*)(bptr[nt] + (kc + 1) * KC);
        }
        bf16x8 af[4];
        #pragma unroll
        for (int mt = 0; mt < 4; ++mt)
            af[mt] = *(const bf16x8*)&a_lds[mt * 16 + m15][kc * KC + q * 8];
        #pragma unroll
        for (int nt = 0; nt < 4; ++nt)
            #pragma unroll
            for (int mt = 0; mt < 4; ++mt)
                acc[mt][nt] = __builtin_amdgcn_mfma_f32_16x16x32_bf16(af[mt], bcur[nt], acc[mt][nt], 0, 0, 0);
        #pragma unroll
        for (int nt = 0; nt < 4; ++nt) bcur[nt] = bnxt[nt];
    }

    // ---- epilogue: msg = relu(acc + b2) * edgeval ; sum edges -> agg[b,t,n,:] ----
    float b2v[4];
    #pragma unroll
    for (int nt = 0; nt < 4; ++nt) b2v[nt] = b_msg2[wbase + nt * 16 + m15];

    #pragma unroll
    for (int tt = 0; tt < 2; ++tt) {
        const int t = t0 + tt;
        #pragma unroll
        for (int nt = 0; nt < 4; ++nt) {
            float part = 0.f;
            #pragma unroll
            for (int ml = 0; ml < 2; ++ml) {
                const int mt = tt * 2 + ml;
                #pragma unroll
                for (int reg = 0; reg < 4; ++reg) {
                    const int ei = (ml * 16 + q * 4 + reg);    // C-layout row = q*4+reg
                    part += ev_lds[ei] * fmaxf(acc[mt][nt][reg] + b2v[nt], 0.f);
                }
            }
            part += __shfl_xor(part, 16, 64);
            part += __shfl_xor(part, 32, 64);
            if (q == 0 && t < TM)
                agg[((((b * TM + t) * NA + n) << 8) + wbase + nt * 16 + m15)] = (bf16)part;
        }
    }
}

// ---------------------------------------------------------------- K3: out MLP 288->256->256->1
// block per 64 (b,t,n) rows. B operands direct global->register, double-buffered.
__global__ __launch_bounds__(256) void k3_out(
    const bf16* __restrict__ agg, const float* __restrict__ inputs,
    const bf16* __restrict__ w1ot, const bf16* __restrict__ w2ot,
    const float* __restrict__ b_out1, const float* __restrict__ b_out2,
    const float* __restrict__ w_out3, const float* __restrict__ b_out3,
    float* __restrict__ out)
{
    __shared__ bf16 a1[64][288 + APAD];        // 37888 B; reused as layer-2 activations
    __shared__ float red[256];

    const int R0 = blockIdx.x * 64;
    const int tid = threadIdx.x;
    const int lane = tid & 63, w = tid >> 6;
    const int q = lane >> 4, m15 = lane & 15;
    const int wbase = w * 64;

    // ---- stage A1 = [agg(256) | feat(5) | 0...] ----
    #pragma unroll
    for (int i = 0; i < 8; ++i) {
        const int task = i * 256 + tid;
        const int row = task >> 5, c = task & 31;
        const int R = R0 + row;
        bf16x8 val;
        if (R < NROWS) {
            val = *(const bf16x8*)&agg[(R << 8) + c * 8];
        } else {
            for (int x = 0; x < 8; ++x) val[x] = (bf16)0.f;
        }
        *(bf16x8*)&a1[row][c * 8] = val;
    }
    if (tid < 64) {
        const int R = R0 + tid;
        if (R < NROWS) {
            const int b = R / (TM * NA), rem = R - b * (TM * NA);
            const int t = rem / NA, n = rem - (rem / NA) * NA;
            const float* ip = inputs + (b * NA + n) * TT + t;
            #pragma unroll
            for (int l = 0; l < LAG; ++l) a1[tid][256 + l] = (bf16)ip[l];
            #pragma unroll
            for (int k = 261; k < 288; ++k) a1[tid][k] = (bf16)0.f;
        } else {
            for (int k = 256; k < 288; ++k) a1[tid][k] = (bf16)0.f;
        }
    }

    floatx4 acc[4][4];
    #pragma unroll
    for (int mt = 0; mt < 4; ++mt)
        #pragma unroll
        for (int nt = 0; nt < 4; ++nt)
            acc[mt][nt] = (floatx4){0.f, 0.f, 0.f, 0.f};

    // ---- GEMM1: K=288 (9 chunks), B from w1ot (row stride 288) ----
    const bf16* bptr1[4];
    #pragma unroll
    for (int nt = 0; nt < 4; ++nt)
        bptr1[nt] = w1ot + (wbase + nt * 16 + m15) * 288 + q * 8;

    bf16x8 bcur[4], bnxt[4];
    #pragma unroll
    for (int nt = 0; nt < 4; ++nt) bcur[nt] = *(const bf16x8*)bptr1[nt];

    __syncthreads();   // A1 staged

    #pragma unroll
    for (int kc = 0; kc < 9; ++kc) {
        if (kc < 8) {
            #pragma unroll
            for (int nt = 0; nt < 4; ++nt)
                bnxt[nt] = *(const bf16x8*)(bptr1[nt] + (kc + 1) * KC);
        }
        bf16x8 af[4];
        #pragma unroll
        for (int mt = 0; mt < 4; ++mt)
            af[mt] = *(const bf16x8*)&a1[mt * 16 + m15][kc * KC + q * 8];
        #pragma unroll
        for (int nt = 0; nt < 4; ++nt)
            #pragma unroll
            for (int mt = 0; mt < 4; ++mt)
                acc[mt][nt] = __builtin_amdgcn_mfma_f32_16x16x32_bf16(af[mt], bcur[nt], acc[mt][nt], 0, 0, 0);
        #pragma unroll
        for (int nt = 0; nt < 4; ++nt) bcur[nt] = bnxt[nt];
    }
    __syncthreads();   // all GEMM1 reads of a1 done before overwrite

    // ---- epilogue1: out1 = relu(acc + b_out1) -> a1[:, 0:256] (bf16) ----
    {
        float b1v[4];
        #pragma unroll
        for (int nt = 0; nt < 4; ++nt) b1v[nt] = b_out1[wbase + nt * 16 + m15];
        #pragma unroll
        for (int mt = 0; mt < 4; ++mt)
            #pragma unroll
            for (int nt = 0; nt < 4; ++nt)
                #pragma unroll
                for (int reg = 0; reg < 4; ++reg)
                    a1[mt * 16 + q * 4 + reg][wbase + nt * 16 + m15] =
                        (bf16)fmaxf(acc[mt][nt][reg] + b1v[nt], 0.f);
    }

    #pragma unroll
    for (int mt = 0; mt < 4; ++mt)
        #pragma unroll
        for (int nt = 0; nt < 4; ++nt)
            acc[mt][nt] = (floatx4){0.f, 0.f, 0.f, 0.f};

    // ---- GEMM2: K=256 (8 chunks), B from w2ot (row stride 256) ----
    const bf16* bptr2[4];
    #pragma unroll
    for (int nt = 0; nt < 4; ++nt)
        bptr2[nt] = w2ot + (wbase + nt * 16 + m15) * HID + q * 8;
    #pragma unroll
    for (int nt = 0; nt < 4; ++nt) bcur[nt] = *(const bf16x8*)bptr2[nt];

    __syncthreads();   // epilogue1 writes visible

    #pragma unroll
    for (int kc = 0; kc < 8; ++kc) {
        if (kc < 7) {
            #pragma unroll
            for (int nt = 0; nt < 4; ++nt)
                bnxt[nt] = *(const bf16x8*)(bptr2[nt] + (kc + 1) * KC);
        }
        bf16x8 af[4];
        #pragma unroll
        for (int mt = 0; mt < 4; ++mt)
            af[mt] = *(const bf16x8*)&a1[mt * 16 + m15][kc * KC + q * 8];
        #pragma unroll
        for (int nt = 0; nt < 4; ++nt)
            #pragma unroll
            for (int mt = 0; mt < 4; ++mt)
                acc[mt][nt] = __builtin_amdgcn_mfma_f32_16x16x32_bf16(af[mt], bcur[nt], acc[mt][nt], 0, 0, 0);
        #pragma unroll
        for (int nt = 0; nt < 4; ++nt) bcur[nt] = bnxt[nt];
    }

    // ---- epilogue2: relu(+b_out2), dot with w_out3, reduce over 256 cols ----
    {
        float b2v[4], w3v[4];
        #pragma unroll
        for (int nt = 0; nt < 4; ++nt) {
            const int col = wbase + nt * 16 + m15;
            b2v[nt] = b_out2[col];
            w3v[nt] = w_out3[col];
        }
        #pragma unroll
        for (int mt = 0; mt < 4; ++mt)
            #pragma unroll
            for (int reg = 0; reg < 4; ++reg) {
                float p = 0.f;
                #pragma unroll
                for (int nt = 0; nt < 4; ++nt)
                    p += fmaxf(acc[mt][nt][reg] + b2v[nt], 0.f) * w3v[nt];
                p += __shfl_xor(p, 1, 64);
                p += __shfl_xor(p, 2, 64);
                p += __shfl_xor(p, 4, 64);
                p += __shfl_xor(p, 8, 64);
                if (m15 == 0) red[w * 64 + mt * 16 + q * 4 + reg] = p;
            }
    }
    __syncthreads();
    if (tid < 64) {
        const int R = R0 + tid;
        if (R < NROWS) {
            const float val = red[tid] + red[64 + tid] + red[128 + tid] + red[192 + tid] + b_out3[0];
            const int b = R / (TM * NA), rem = R - b * (TM * NA);
            const int t = rem / NA, n = rem - (rem / NA) * NA;
            out[(b * NA + n) * TM + t] = val;
        }
    }
}

// ----------------------------------------------------------------
extern "C" void kernel_launch(void* const* d_in, const int* in_sizes, int n_in,
                              void* d_out, int out_size, void* d_ws, size_t ws_size,
                              hipStream_t stream) {
    const float* inputs  = (const float*)d_in[0];
    const float* mu      = (const float*)d_in[1];
    const float* logvar  = (const float*)d_in[2];
    const float* eps     = (const float*)d_in[3];
    const float* w_msg1  = (const float*)d_in[6];
    const float* b_msg1  = (const float*)d_in[7];
    const float* w_msg2  = (const float*)d_in[8];
    const float* b_msg2  = (const float*)d_in[9];
    const float* w_out1  = (const float*)d_in[10];
    const float* b_out1  = (const float*)d_in[11];
    const float* w_out2  = (const float*)d_in[12];
    const float* b_out2  = (const float*)d_in[13];
    const float* w_out3  = (const float*)d_in[14];
    const float* b_out3  = (const float*)d_in[15];
    float* out = (float*)d_out;

    // workspace (bf16 elems): u, v, agg = 11700*256 each; W2^T; W_out1'^T (256x288); W_out2^T
    bf16* u    = (bf16*)d_ws;
    bf16* v    = u    + NROWS * HID;
    bf16* aggw = v    + NROWS * HID;
    bf16* w2t  = aggw + NROWS * HID;
    bf16* w1ot = w2t  + HID * HID;
    bf16* w2ot = w1ot + HID * 288;   // total ~18.4 MB

    hipLaunchKernelGGL(k1_prep, dim3(K1UV + 256 + 288 + 256), dim3(256), 0, stream,
                       inputs, w_msg1, b_msg1, w_msg2, w_out1, w_out2,
                       u, v, w2t, w1ot, w2ot);
    hipLaunchKernelGGL(k2_msg, dim3(NB * NA * NTB), dim3(256), 0, stream,
                       u, v, w2t, mu, logvar, eps, b_msg2, aggw);
    hipLaunchKernelGGL(k3_out, dim3((NROWS + 63) / 64), dim3(256), 0, stream,
                       aggw, inputs, w1ot, w2ot, b_out1, b_out2, w_out3, b_out3, out);
}

// Round 5
// 175.081 us; speedup vs baseline: 6.2892x; 1.2742x over previous
//
#include <hip/hip_runtime.h>

#define LAG 5
#define HID 256
#define NA 30
#define NE 870
#define TM 195
#define TT 200
#define NB 2
#define EPN 29
#define NTB 98                 // ceil(195/2) time-tiles of 2
#define NROWS (NB * TM * NA)   // 11700 (b,t,n) rows
#define APAD 8
#define KC 32                  // K-chunk (1 MFMA k-step)
#define UVB 1463               // ceil(11700/8) u,v blocks in k1
#define W2F_ELEMS (HID * HID)  // 65536
#define W1F_ELEMS (HID * 288)  // 73728
#define W2OF_ELEMS (HID * HID) // 65536

typedef __bf16 bf16;
typedef __bf16 bf16x8 __attribute__((ext_vector_type(8)));
typedef float floatx4 __attribute__((ext_vector_type(4)));

// ---------------------------------------------------------------- K1: prep
// [0,1463): u,v (8 rows/block) ; [1463,1495): W2 frag ; [1495,1531): Wout1 frag ; [1531,1563): Wout2 frag
// Fragment order: chunk = (wave*4+nt)*KCHUNKS + kc ; element offset = (chunk*64 + lane)*8.
// Lane holds B[col = wv*64+nt*16+(lane&15)][k = kc*32+(lane>>4)*8 .. +8] -> coalesced 16B/lane loads.
__global__ __launch_bounds__(256) void k1_prep(
    const float* __restrict__ inputs, const float* __restrict__ w_msg1,
    const float* __restrict__ b_msg1, const float* __restrict__ w_msg2,
    const float* __restrict__ w_out1, const float* __restrict__ w_out2,
    bf16* __restrict__ u, bf16* __restrict__ v, bf16* __restrict__ w2frag,
    bf16* __restrict__ w1frag, bf16* __restrict__ w2ofrag)
{
    const int bid = blockIdx.x, tid = threadIdx.x;
    if (bid < UVB) {
        __shared__ float feats8[8][LAG];
        const int r0 = bid * 8;
        if (tid < 8 * LAG) {
            const int i = tid / LAG, l = tid % LAG;
            const int r = r0 + i;
            float fv = 0.f;
            if (r < NROWS) {
                const int b = r / (TM * NA), rem = r % (TM * NA);
                const int t = rem / NA, n = rem % NA;
                fv = inputs[(b * NA + n) * TT + t + l];
            }
            feats8[i][l] = fv;
        }
        float w1c[2 * LAG];
        #pragma unroll
        for (int k = 0; k < 2 * LAG; ++k) w1c[k] = w_msg1[k * HID + tid];
        const float bb = b_msg1[tid];
        __syncthreads();
        #pragma unroll
        for (int i = 0; i < 8; ++i) {
            const int r = r0 + i;
            if (r < NROWS) {
                float ua = bb, va = 0.f;
                #pragma unroll
                for (int l = 0; l < LAG; ++l) {
                    ua = fmaf(feats8[i][l], w1c[l], ua);
                    va = fmaf(feats8[i][l], w1c[LAG + l], va);
                }
                u[(r << 8) + tid] = (bf16)ua;
                v[(r << 8) + tid] = (bf16)va;
            }
        }
    } else if (bid < UVB + 32) {                      // W2^T frag (8 k-chunks)
        const int fidx = (bid - UVB) * 256 + tid;     // [0, 8192)
        const int lane = fidx & 63;
        const int kc = (fidx >> 6) & 7;
        const int ntc = fidx >> 9;
        const int col = (ntc >> 2) * 64 + (ntc & 3) * 16 + (lane & 15);
        const int kb = kc * KC + (lane >> 4) * 8;
        bf16x8 vv;
        #pragma unroll
        for (int x = 0; x < 8; ++x) vv[x] = (bf16)w_msg2[(kb + x) * HID + col];
        *(bf16x8*)&w2frag[fidx * 8] = vv;
    } else if (bid < UVB + 32 + 36) {                 // W_out1' frag (9 k-chunks, K=288)
        const int fidx = (bid - (UVB + 32)) * 256 + tid;  // [0, 9216)
        const int lane = fidx & 63;
        const int kc = (fidx >> 6) % 9;
        const int ntc = fidx / (64 * 9);
        const int col = (ntc >> 2) * 64 + (ntc & 3) * 16 + (lane & 15);
        const int kb = kc * KC + (lane >> 4) * 8;
        bf16x8 vv;
        #pragma unroll
        for (int x = 0; x < 8; ++x) {
            const int k = kb + x;
            float val;
            if (k < 256)      val = w_out1[(5 + k) * HID + col];   // agg part (rows 5..260)
            else if (k < 261) val = w_out1[(k - 256) * HID + col]; // feat part (rows 0..4)
            else              val = 0.f;                           // K-pad
            vv[x] = (bf16)val;
        }
        *(bf16x8*)&w1frag[fidx * 8] = vv;
    } else {                                          // W_out2^T frag (8 k-chunks)
        const int fidx = (bid - (UVB + 32 + 36)) * 256 + tid;
        const int lane = fidx & 63;
        const int kc = (fidx >> 6) & 7;
        const int ntc = fidx >> 9;
        const int col = (ntc >> 2) * 64 + (ntc & 3) * 16 + (lane & 15);
        const int kb = kc * KC + (lane >> 4) * 8;
        bf16x8 vv;
        #pragma unroll
        for (int x = 0; x < 8; ++x) vv[x] = (bf16)w_out2[(kb + x) * HID + col];
        *(bf16x8*)&w2ofrag[fidx * 8] = vv;
    }
}

// ---------------------------------------------------------------- K2: msg MLP + edge-weighted aggregation
// block per (b, n, t-tile of 2). M=64, N=256, K=256. B from frag-order global (coalesced), no K-loop barriers.
__global__ __launch_bounds__(256) void k2_msg(
    const bf16* __restrict__ u, const bf16* __restrict__ v,
    const bf16* __restrict__ w2frag,
    const float* __restrict__ mu, const float* __restrict__ logvar,
    const float* __restrict__ eps, const float* __restrict__ b_msg2,
    bf16* __restrict__ agg)
{
    __shared__ bf16 a_lds[64][HID + APAD];     // 33792 B, row stride 132 dw (=4 mod 32: 2-way max)
    __shared__ float ev_lds[32];

    const int bid = blockIdx.x;
    const int n  = bid % NA;
    const int tb = (bid / NA) % NTB;
    const int b  = bid / (NA * NTB);
    const int t0 = tb * 2;
    const int tid = threadIdx.x;
    const int lane = tid & 63, w = tid >> 6;
    const int q = lane >> 4, m15 = lane & 15;
    const int wbase = w * 64;

    if (tid < 32) {
        float evv = 0.f;
        if (tid < EPN) {
            const int e = b * NE + n * EPN + tid;
            evv = eps[e] * __expf(0.5f * logvar[e]) + mu[e];
        }
        ev_lds[tid] = evv;
    }

    // ---- stage A = relu(u[send] + v[recv]) : 64 rows x 256 k ----
    #pragma unroll
    for (int i = 0; i < 8; ++i) {
        const int task = i * 256 + tid;
        const int row = task >> 5, c = task & 31;
        const int tt = row >> 5, ei = row & 31;
        bf16x8 out8;
        if (ei < EPN) {
            int t = t0 + tt; if (t > TM - 1) t = TM - 1;     // clamp (store guarded later)
            const int j = ei + (ei >= n);
            const bf16x8 uu = *(const bf16x8*)(u + ((((b * TM + t) * NA + j) << 8) + c * 8));
            const bf16x8 vv = *(const bf16x8*)(v + ((((b * TM + t) * NA + n) << 8) + c * 8));
            #pragma unroll
            for (int x = 0; x < 8; ++x)
                out8[x] = (bf16)fmaxf((float)uu[x] + (float)vv[x], 0.f);
        } else {
            #pragma unroll
            for (int x = 0; x < 8; ++x) out8[x] = (bf16)0.f;  // zero pad rows
        }
        *(bf16x8*)&a_lds[row][c * 8] = out8;
    }

    // frag-order B pointers: element offset = (((w*4+nt)*8 + kc) << 9) + (lane << 3)
    const bf16* bbase = w2frag + (lane << 3);
    bf16x8 bcur[4], bnxt[4];
    #pragma unroll
    for (int nt = 0; nt < 4; ++nt)
        bcur[nt] = *(const bf16x8*)(bbase + (((w * 4 + nt) * 8 + 0) << 9));

    floatx4 acc[4][4];
    #pragma unroll
    for (int mt = 0; mt < 4; ++mt)
        #pragma unroll
        for (int nt = 0; nt < 4; ++nt)
            acc[mt][nt] = (floatx4){0.f, 0.f, 0.f, 0.f};

    __syncthreads();   // A staged (the only barrier)

    #pragma unroll
    for (int kc = 0; kc < 8; ++kc) {
        if (kc < 7) {
            #pragma unroll
            for (int nt = 0; nt < 4; ++nt)
                bnxt[nt] = *(const bf16x8*)(bbase + (((w * 4 + nt) * 8 + kc + 1) << 9));
        }
        bf16x8 af[4];
        #pragma unroll
        for (int mt = 0; mt < 4; ++mt)
            af[mt] = *(const bf16x8*)&a_lds[mt * 16 + m15][kc * KC + q * 8];
        #pragma unroll
        for (int nt = 0; nt < 4; ++nt)
            #pragma unroll
            for (int mt = 0; mt < 4; ++mt)
                acc[mt][nt] = __builtin_amdgcn_mfma_f32_16x16x32_bf16(af[mt], bcur[nt], acc[mt][nt], 0, 0, 0);
        #pragma unroll
        for (int nt = 0; nt < 4; ++nt) bcur[nt] = bnxt[nt];
    }

    // ---- epilogue: msg = relu(acc + b2) * edgeval ; sum edges -> agg[b,t,n,:] ----
    float b2v[4];
    #pragma unroll
    for (int nt = 0; nt < 4; ++nt) b2v[nt] = b_msg2[wbase + nt * 16 + m15];

    #pragma unroll
    for (int tt = 0; tt < 2; ++tt) {
        const int t = t0 + tt;
        #pragma unroll
        for (int nt = 0; nt < 4; ++nt) {
            float part = 0.f;
            #pragma unroll
            for (int ml = 0; ml < 2; ++ml) {
                const int mt = tt * 2 + ml;
                #pragma unroll
                for (int reg = 0; reg < 4; ++reg) {
                    const int ei = (ml * 16 + q * 4 + reg);    // C-layout row = q*4+reg
                    part += ev_lds[ei] * fmaxf(acc[mt][nt][reg] + b2v[nt], 0.f);
                }
            }
            part += __shfl_xor(part, 16, 64);
            part += __shfl_xor(part, 32, 64);
            if (q == 0 && t < TM)
                agg[((((b * TM + t) * NA + n) << 8) + wbase + nt * 16 + m15)] = (bf16)part;
        }
    }
}

// ---------------------------------------------------------------- K3: out MLP 288->256->256->1
// block per 16 rows (732 blocks, ~2.9/CU). B from frag-order global, double-buffered.
__global__ __launch_bounds__(256) void k3_out(
    const bf16* __restrict__ agg, const float* __restrict__ inputs,
    const bf16* __restrict__ w1frag, const bf16* __restrict__ w2ofrag,
    const float* __restrict__ b_out1, const float* __restrict__ b_out2,
    const float* __restrict__ w_out3, const float* __restrict__ b_out3,
    float* __restrict__ out)
{
    __shared__ bf16 a1[16][288 + APAD];        // 9472 B; stride 148 dw (=20 mod 32: 2-way max)
    __shared__ float red[4][16];

    const int R0 = blockIdx.x * 16;
    const int tid = threadIdx.x;
    const int lane = tid & 63, w = tid >> 6;
    const int q = lane >> 4, m15 = lane & 15;
    const int wbase = w * 64;

    // ---- stage A1 = [agg(256) | feat(5) | 0...] ----
    #pragma unroll
    for (int i = 0; i < 2; ++i) {
        const int task = i * 256 + tid;                // [0,512): 16 rows x 32 chunks
        const int row = task >> 5, c = task & 31;
        const int R = R0 + row;
        bf16x8 val;
        if (R < NROWS) {
            val = *(const bf16x8*)&agg[(R << 8) + c * 8];
        } else {
            for (int x = 0; x < 8; ++x) val[x] = (bf16)0.f;
        }
        *(bf16x8*)&a1[row][c * 8] = val;
    }
    if (tid < 16) {
        const int R = R0 + tid;
        if (R < NROWS) {
            const int b = R / (TM * NA), rem = R % (TM * NA);
            const int t = rem / NA, n = rem % NA;
            const float* ip = inputs + (b * NA + n) * TT + t;
            #pragma unroll
            for (int l = 0; l < LAG; ++l) a1[tid][256 + l] = (bf16)ip[l];
            #pragma unroll
            for (int k = 261; k < 288; ++k) a1[tid][k] = (bf16)0.f;
        } else {
            for (int k = 256; k < 288; ++k) a1[tid][k] = (bf16)0.f;
        }
    }

    floatx4 acc[4];
    #pragma unroll
    for (int nt = 0; nt < 4; ++nt) acc[nt] = (floatx4){0.f, 0.f, 0.f, 0.f};

    // ---- GEMM1: K=288 (9 chunks) ----
    const bf16* b1base = w1frag + (lane << 3);
    bf16x8 bcur[4], bnxt[4];
    #pragma unroll
    for (int nt = 0; nt < 4; ++nt)
        bcur[nt] = *(const bf16x8*)(b1base + (((w * 4 + nt) * 9 + 0) << 9));

    __syncthreads();   // A1 staged

    #pragma unroll
    for (int kc = 0; kc < 9; ++kc) {
        if (kc < 8) {
            #pragma unroll
            for (int nt = 0; nt < 4; ++nt)
                bnxt[nt] = *(const bf16x8*)(b1base + (((w * 4 + nt) * 9 + kc + 1) << 9));
        }
        const bf16x8 af = *(const bf16x8*)&a1[m15][kc * KC + q * 8];
        #pragma unroll
        for (int nt = 0; nt < 4; ++nt)
            acc[nt] = __builtin_amdgcn_mfma_f32_16x16x32_bf16(af, bcur[nt], acc[nt], 0, 0, 0);
        #pragma unroll
        for (int nt = 0; nt < 4; ++nt) bcur[nt] = bnxt[nt];
    }
    __syncthreads();   // all GEMM1 reads of a1 done before overwrite

    // ---- epilogue1: out1 = relu(acc + b_out1) -> a1[:, 0:256] ----
    {
        float b1v[4];
        #pragma unroll
        for (int nt = 0; nt < 4; ++nt) b1v[nt] = b_out1[wbase + nt * 16 + m15];
        #pragma unroll
        for (int nt = 0; nt < 4; ++nt)
            #pragma unroll
            for (int reg = 0; reg < 4; ++reg)
                a1[q * 4 + reg][wbase + nt * 16 + m15] =
                    (bf16)fmaxf(acc[nt][reg] + b1v[nt], 0.f);
    }

    #pragma unroll
    for (int nt = 0; nt < 4; ++nt) acc[nt] = (floatx4){0.f, 0.f, 0.f, 0.f};

    // ---- GEMM2: K=256 (8 chunks) ----
    const bf16* b2base = w2ofrag + (lane << 3);
    #pragma unroll
    for (int nt = 0; nt < 4; ++nt)
        bcur[nt] = *(const bf16x8*)(b2base + (((w * 4 + nt) * 8 + 0) << 9));

    __syncthreads();   // epilogue1 writes visible

    #pragma unroll
    for (int kc = 0; kc < 8; ++kc) {
        if (kc < 7) {
            #pragma unroll
            for (int nt = 0; nt < 4; ++nt)
                bnxt[nt] = *(const bf16x8*)(b2base + (((w * 4 + nt) * 8 + kc + 1) << 9));
        }
        const bf16x8 af = *(const bf16x8*)&a1[m15][kc * KC + q * 8];
        #pragma unroll
        for (int nt = 0; nt < 4; ++nt)
            acc[nt] = __builtin_amdgcn_mfma_f32_16x16x32_bf16(af, bcur[nt], acc[nt], 0, 0, 0);
        #pragma unroll
        for (int nt = 0; nt < 4; ++nt) bcur[nt] = bnxt[nt];
    }

    // ---- epilogue2: relu(+b_out2), dot w_out3, reduce over 256 cols ----
    {
        float b2v[4], w3v[4];
        #pragma unroll
        for (int nt = 0; nt < 4; ++nt) {
            const int col = wbase + nt * 16 + m15;
            b2v[nt] = b_out2[col];
            w3v[nt] = w_out3[col];
        }
        #pragma unroll
        for (int reg = 0; reg < 4; ++reg) {
            float p = 0.f;
            #pragma unroll
            for (int nt = 0; nt < 4; ++nt)
                p += fmaxf(acc[nt][reg] + b2v[nt], 0.f) * w3v[nt];
            p += __shfl_xor(p, 1, 64);
            p += __shfl_xor(p, 2, 64);
            p += __shfl_xor(p, 4, 64);
            p += __shfl_xor(p, 8, 64);
            if (m15 == 0) red[w][q * 4 + reg] = p;
        }
    }
    __syncthreads();
    if (tid < 16) {
        const int R = R0 + tid;
        if (R < NROWS) {
            const float val = red[0][tid] + red[1][tid] + red[2][tid] + red[3][tid] + b_out3[0];
            const int b = R / (TM * NA), rem = R % (TM * NA);
            const int t = rem / NA, n = rem % NA;
            out[(b * NA + n) * TM + t] = val;
        }
    }
}

// ----------------------------------------------------------------
extern "C" void kernel_launch(void* const* d_in, const int* in_sizes, int n_in,
                              void* d_out, int out_size, void* d_ws, size_t ws_size,
                              hipStream_t stream) {
    const float* inputs  = (const float*)d_in[0];
    const float* mu      = (const float*)d_in[1];
    const float* logvar  = (const float*)d_in[2];
    const float* eps     = (const float*)d_in[3];
    const float* w_msg1  = (const float*)d_in[6];
    const float* b_msg1  = (const float*)d_in[7];
    const float* w_msg2  = (const float*)d_in[8];
    const float* b_msg2  = (const float*)d_in[9];
    const float* w_out1  = (const float*)d_in[10];
    const float* b_out1  = (const float*)d_in[11];
    const float* w_out2  = (const float*)d_in[12];
    const float* b_out2  = (const float*)d_in[13];
    const float* w_out3  = (const float*)d_in[14];
    const float* b_out3  = (const float*)d_in[15];
    float* out = (float*)d_out;

    // workspace (bf16 elems): u, v, agg (11700*256 each); frag-order W2, Wout1, Wout2
    bf16* u       = (bf16*)d_ws;
    bf16* v       = u       + NROWS * HID;
    bf16* aggw    = v       + NROWS * HID;
    bf16* w2frag  = aggw    + NROWS * HID;
    bf16* w1frag  = w2frag  + W2F_ELEMS;
    bf16* w2ofrag = w1frag  + W1F_ELEMS;   // total ~18.4 MB

    hipLaunchKernelGGL(k1_prep, dim3(UVB + 32 + 36 + 32), dim3(256), 0, stream,
                       inputs, w_msg1, b_msg1, w_msg2, w_out1, w_out2,
                       u, v, w2frag, w1frag, w2ofrag);
    hipLaunchKernelGGL(k2_msg, dim3(NB * NA * NTB), dim3(256), 0, stream,
                       u, v, w2frag, mu, logvar, eps, b_msg2, aggw);
    hipLaunchKernelGGL(k3_out, dim3((NROWS + 15) / 16), dim3(256), 0, stream,
                       aggw, inputs, w1frag, w2ofrag, b_out1, b_out2, w_out3, b_out3, out);
}

// Round 6
// 168.774 us; speedup vs baseline: 6.5243x; 1.0374x over previous
//
#include <hip/hip_runtime.h>

#define LAG 5
#define HID 256
#define NA 30
#define NE 870
#define TM 195
#define TT 200
#define NB 2
#define EPN 29
#define NTB 98                 // ceil(195/2) time-tiles of 2
#define NROWS (NB * TM * NA)   // 11700 (b,t,n) rows
#define APAD 8
#define KC 32                  // K-chunk (1 MFMA k-step)
#define UVB 1463               // ceil(11700/8) u,v blocks in k1
#define W2F_ELEMS (HID * HID)  // 65536
#define W1F_ELEMS (HID * 288)  // 73728
#define W2OF_ELEMS (HID * HID) // 65536

typedef __bf16 bf16;
typedef __bf16 bf16x8 __attribute__((ext_vector_type(8)));
typedef float floatx4 __attribute__((ext_vector_type(4)));

// ---------------------------------------------------------------- K1: prep
// [0,1463): u,v (8 rows/block) ; [1463,1495): W2 frag ; [1495,1531): Wout1 frag ; [1531,1563): Wout2 frag
// Fragment order: chunk = col/16 (16 col-chunks) ; element offset = ((chunk*KCHUNKS + kc)*64 + lane)*8.
// Lane holds B[col = chunk*16+(lane&15)][k = kc*32+(lane>>4)*8 .. +8] -> coalesced 16B/lane loads.
__global__ __launch_bounds__(256) void k1_prep(
    const float* __restrict__ inputs, const float* __restrict__ w_msg1,
    const float* __restrict__ b_msg1, const float* __restrict__ w_msg2,
    const float* __restrict__ w_out1, const float* __restrict__ w_out2,
    bf16* __restrict__ u, bf16* __restrict__ v, bf16* __restrict__ w2frag,
    bf16* __restrict__ w1frag, bf16* __restrict__ w2ofrag)
{
    const int bid = blockIdx.x, tid = threadIdx.x;
    if (bid < UVB) {
        __shared__ float feats8[8][LAG];
        const int r0 = bid * 8;
        if (tid < 8 * LAG) {
            const int i = tid / LAG, l = tid % LAG;
            const int r = r0 + i;
            float fv = 0.f;
            if (r < NROWS) {
                const int b = r / (TM * NA), rem = r % (TM * NA);
                const int t = rem / NA, n = rem % NA;
                fv = inputs[(b * NA + n) * TT + t + l];
            }
            feats8[i][l] = fv;
        }
        float w1c[2 * LAG];
        #pragma unroll
        for (int k = 0; k < 2 * LAG; ++k) w1c[k] = w_msg1[k * HID + tid];
        const float bb = b_msg1[tid];
        __syncthreads();
        #pragma unroll
        for (int i = 0; i < 8; ++i) {
            const int r = r0 + i;
            if (r < NROWS) {
                float ua = bb, va = 0.f;
                #pragma unroll
                for (int l = 0; l < LAG; ++l) {
                    ua = fmaf(feats8[i][l], w1c[l], ua);
                    va = fmaf(feats8[i][l], w1c[LAG + l], va);
                }
                u[(r << 8) + tid] = (bf16)ua;
                v[(r << 8) + tid] = (bf16)va;
            }
        }
    } else if (bid < UVB + 32) {                      // W2^T frag (8 k-chunks)
        const int fidx = (bid - UVB) * 256 + tid;     // [0, 8192)
        const int lane = fidx & 63;
        const int kc = (fidx >> 6) & 7;
        const int ntc = fidx >> 9;                    // chunk = col/16
        const int col = ntc * 16 + (lane & 15);
        const int kb = kc * KC + (lane >> 4) * 8;
        bf16x8 vv;
        #pragma unroll
        for (int x = 0; x < 8; ++x) vv[x] = (bf16)w_msg2[(kb + x) * HID + col];
        *(bf16x8*)&w2frag[fidx * 8] = vv;
    } else if (bid < UVB + 32 + 36) {                 // W_out1' frag (9 k-chunks, K=288)
        const int fidx = (bid - (UVB + 32)) * 256 + tid;  // [0, 9216)
        const int lane = fidx & 63;
        const int kc = (fidx >> 6) % 9;
        const int ntc = fidx / (64 * 9);
        const int col = ntc * 16 + (lane & 15);
        const int kb = kc * KC + (lane >> 4) * 8;
        bf16x8 vv;
        #pragma unroll
        for (int x = 0; x < 8; ++x) {
            const int k = kb + x;
            float val;
            if (k < 256)      val = w_out1[(5 + k) * HID + col];   // agg part (rows 5..260)
            else if (k < 261) val = w_out1[(k - 256) * HID + col]; // feat part (rows 0..4)
            else              val = 0.f;                           // K-pad
            vv[x] = (bf16)val;
        }
        *(bf16x8*)&w1frag[fidx * 8] = vv;
    } else {                                          // W_out2^T frag (8 k-chunks)
        const int fidx = (bid - (UVB + 32 + 36)) * 256 + tid;
        const int lane = fidx & 63;
        const int kc = (fidx >> 6) & 7;
        const int ntc = fidx >> 9;
        const int col = ntc * 16 + (lane & 15);
        const int kb = kc * KC + (lane >> 4) * 8;
        bf16x8 vv;
        #pragma unroll
        for (int x = 0; x < 8; ++x) vv[x] = (bf16)w_out2[(kb + x) * HID + col];
        *(bf16x8*)&w2ofrag[fidx * 8] = vv;
    }
}

// ---------------------------------------------------------------- K2: msg MLP + edge-weighted aggregation
// 512 threads / 8 waves; block per (b, n, t-tile of 2). M=64, N=256 (32/wave), K=256.
// B from frag-order global (coalesced), no K-loop barriers.
__global__ __launch_bounds__(512) void k2_msg(
    const bf16* __restrict__ u, const bf16* __restrict__ v,
    const bf16* __restrict__ w2frag,
    const float* __restrict__ mu, const float* __restrict__ logvar,
    const float* __restrict__ eps, const float* __restrict__ b_msg2,
    bf16* __restrict__ agg)
{
    __shared__ bf16 a_lds[64][HID + APAD];     // 33792 B
    __shared__ float ev_lds[32];

    const int bid = blockIdx.x;
    const int n  = bid % NA;
    const int tb = (bid / NA) % NTB;
    const int b  = bid / (NA * NTB);
    const int t0 = tb * 2;
    const int tid = threadIdx.x;
    const int lane = tid & 63, w = tid >> 6;   // w in [0,8)
    const int q = lane >> 4, m15 = lane & 15;
    const int wbase = w * 32;                  // 32-col slice per wave

    if (tid < 32) {
        float evv = 0.f;
        if (tid < EPN) {
            const int e = b * NE + n * EPN + tid;
            evv = eps[e] * __expf(0.5f * logvar[e]) + mu[e];
        }
        ev_lds[tid] = evv;
    }

    // ---- stage A = relu(u[send] + v[recv]) : 64 rows x 32 chunks = 2048 tasks ----
    #pragma unroll
    for (int i = 0; i < 4; ++i) {
        const int task = i * 512 + tid;
        const int row = task >> 5, c = task & 31;
        const int tt = row >> 5, ei = row & 31;
        bf16x8 out8;
        if (ei < EPN) {
            int t = t0 + tt; if (t > TM - 1) t = TM - 1;     // clamp (store guarded later)
            const int j = ei + (ei >= n);
            const bf16x8 uu = *(const bf16x8*)(u + ((((b * TM + t) * NA + j) << 8) + c * 8));
            const bf16x8 vv = *(const bf16x8*)(v + ((((b * TM + t) * NA + n) << 8) + c * 8));
            #pragma unroll
            for (int x = 0; x < 8; ++x)
                out8[x] = (bf16)fmaxf((float)uu[x] + (float)vv[x], 0.f);
        } else {
            #pragma unroll
            for (int x = 0; x < 8; ++x) out8[x] = (bf16)0.f;  // zero pad rows
        }
        *(bf16x8*)&a_lds[row][c * 8] = out8;
    }

    // frag-order B: chunk = col/16 = w*2+nt ; offset = ((chunk*8 + kc) << 9) + (lane << 3)
    const bf16* bbase = w2frag + (lane << 3);
    bf16x8 bcur[2], bnxt[2];
    #pragma unroll
    for (int nt = 0; nt < 2; ++nt)
        bcur[nt] = *(const bf16x8*)(bbase + (((w * 2 + nt) * 8 + 0) << 9));

    floatx4 acc[4][2];
    #pragma unroll
    for (int mt = 0; mt < 4; ++mt)
        #pragma unroll
        for (int nt = 0; nt < 2; ++nt)
            acc[mt][nt] = (floatx4){0.f, 0.f, 0.f, 0.f};

    __syncthreads();   // A staged (the only barrier)

    #pragma unroll
    for (int kc = 0; kc < 8; ++kc) {
        if (kc < 7) {
            #pragma unroll
            for (int nt = 0; nt < 2; ++nt)
                bnxt[nt] = *(const bf16x8*)(bbase + (((w * 2 + nt) * 8 + kc + 1) << 9));
        }
        bf16x8 af[4];
        #pragma unroll
        for (int mt = 0; mt < 4; ++mt)
            af[mt] = *(const bf16x8*)&a_lds[mt * 16 + m15][kc * KC + q * 8];
        #pragma unroll
        for (int nt = 0; nt < 2; ++nt)
            #pragma unroll
            for (int mt = 0; mt < 4; ++mt)
                acc[mt][nt] = __builtin_amdgcn_mfma_f32_16x16x32_bf16(af[mt], bcur[nt], acc[mt][nt], 0, 0, 0);
        #pragma unroll
        for (int nt = 0; nt < 2; ++nt) bcur[nt] = bnxt[nt];
    }

    // ---- epilogue: msg = relu(acc + b2) * edgeval ; sum edges -> agg[b,t,n,:] ----
    float b2v[2];
    #pragma unroll
    for (int nt = 0; nt < 2; ++nt) b2v[nt] = b_msg2[wbase + nt * 16 + m15];

    #pragma unroll
    for (int tt = 0; tt < 2; ++tt) {
        const int t = t0 + tt;
        #pragma unroll
        for (int nt = 0; nt < 2; ++nt) {
            float part = 0.f;
            #pragma unroll
            for (int ml = 0; ml < 2; ++ml) {
                const int mt = tt * 2 + ml;
                #pragma unroll
                for (int reg = 0; reg < 4; ++reg) {
                    const int ei = (ml * 16 + q * 4 + reg);    // C-layout row = q*4+reg
                    part += ev_lds[ei] * fmaxf(acc[mt][nt][reg] + b2v[nt], 0.f);
                }
            }
            part += __shfl_xor(part, 16, 64);
            part += __shfl_xor(part, 32, 64);
            if (q == 0 && t < TM)
                agg[((((b * TM + t) * NA + n) << 8) + wbase + nt * 16 + m15)] = (bf16)part;
        }
    }
}

// ---------------------------------------------------------------- K3: out MLP 288->256->256->1
// block per 16 rows (732 blocks). B from frag-order global, double-buffered.
// chunk = col/16 = w*4+nt (4 waves, 64-col slice each).
__global__ __launch_bounds__(256) void k3_out(
    const bf16* __restrict__ agg, const float* __restrict__ inputs,
    const bf16* __restrict__ w1frag, const bf16* __restrict__ w2ofrag,
    const float* __restrict__ b_out1, const float* __restrict__ b_out2,
    const float* __restrict__ w_out3, const float* __restrict__ b_out3,
    float* __restrict__ out)
{
    __shared__ bf16 a1[16][288 + APAD];        // 9472 B
    __shared__ float red[4][16];

    const int R0 = blockIdx.x * 16;
    const int tid = threadIdx.x;
    const int lane = tid & 63, w = tid >> 6;
    const int q = lane >> 4, m15 = lane & 15;
    const int wbase = w * 64;

    // ---- stage A1 = [agg(256) | feat(5) | 0...] ----
    #pragma unroll
    for (int i = 0; i < 2; ++i) {
        const int task = i * 256 + tid;                // [0,512): 16 rows x 32 chunks
        const int row = task >> 5, c = task & 31;
        const int R = R0 + row;
        bf16x8 val;
        if (R < NROWS) {
            val = *(const bf16x8*)&agg[(R << 8) + c * 8];
        } else {
            for (int x = 0; x < 8; ++x) val[x] = (bf16)0.f;
        }
        *(bf16x8*)&a1[row][c * 8] = val;
    }
    if (tid < 16) {
        const int R = R0 + tid;
        if (R < NROWS) {
            const int b = R / (TM * NA), rem = R % (TM * NA);
            const int t = rem / NA, n = rem % NA;
            const float* ip = inputs + (b * NA + n) * TT + t;
            #pragma unroll
            for (int l = 0; l < LAG; ++l) a1[tid][256 + l] = (bf16)ip[l];
            #pragma unroll
            for (int k = 261; k < 288; ++k) a1[tid][k] = (bf16)0.f;
        } else {
            for (int k = 256; k < 288; ++k) a1[tid][k] = (bf16)0.f;
        }
    }

    floatx4 acc[4];
    #pragma unroll
    for (int nt = 0; nt < 4; ++nt) acc[nt] = (floatx4){0.f, 0.f, 0.f, 0.f};

    // ---- GEMM1: K=288 (9 chunks) ----
    const bf16* b1base = w1frag + (lane << 3);
    bf16x8 bcur[4], bnxt[4];
    #pragma unroll
    for (int nt = 0; nt < 4; ++nt)
        bcur[nt] = *(const bf16x8*)(b1base + (((w * 4 + nt) * 9 + 0) << 9));

    __syncthreads();   // A1 staged

    #pragma unroll
    for (int kc = 0; kc < 9; ++kc) {
        if (kc < 8) {
            #pragma unroll
            for (int nt = 0; nt < 4; ++nt)
                bnxt[nt] = *(const bf16x8*)(b1base + (((w * 4 + nt) * 9 + kc + 1) << 9));
        }
        const bf16x8 af = *(const bf16x8*)&a1[m15][kc * KC + q * 8];
        #pragma unroll
        for (int nt = 0; nt < 4; ++nt)
            acc[nt] = __builtin_amdgcn_mfma_f32_16x16x32_bf16(af, bcur[nt], acc[nt], 0, 0, 0);
        #pragma unroll
        for (int nt = 0; nt < 4; ++nt) bcur[nt] = bnxt[nt];
    }
    __syncthreads();   // all GEMM1 reads of a1 done before overwrite

    // ---- epilogue1: out1 = relu(acc + b_out1) -> a1[:, 0:256] ----
    {
        float b1v[4];
        #pragma unroll
        for (int nt = 0; nt < 4; ++nt) b1v[nt] = b_out1[wbase + nt * 16 + m15];
        #pragma unroll
        for (int nt = 0; nt < 4; ++nt)
            #pragma unroll
            for (int reg = 0; reg < 4; ++reg)
                a1[q * 4 + reg][wbase + nt * 16 + m15] =
                    (bf16)fmaxf(acc[nt][reg] + b1v[nt], 0.f);
    }

    #pragma unroll
    for (int nt = 0; nt < 4; ++nt) acc[nt] = (floatx4){0.f, 0.f, 0.f, 0.f};

    // ---- GEMM2: K=256 (8 chunks) ----
    const bf16* b2base = w2ofrag + (lane << 3);
    #pragma unroll
    for (int nt = 0; nt < 4; ++nt)
        bcur[nt] = *(const bf16x8*)(b2base + (((w * 4 + nt) * 8 + 0) << 9));

    __syncthreads();   // epilogue1 writes visible

    #pragma unroll
    for (int kc = 0; kc < 8; ++kc) {
        if (kc < 7) {
            #pragma unroll
            for (int nt = 0; nt < 4; ++nt)
                bnxt[nt] = *(const bf16x8*)(b2base + (((w * 4 + nt) * 8 + kc + 1) << 9));
        }
        const bf16x8 af = *(const bf16x8*)&a1[m15][kc * KC + q * 8];
        #pragma unroll
        for (int nt = 0; nt < 4; ++nt)
            acc[nt] = __builtin_amdgcn_mfma_f32_16x16x32_bf16(af, bcur[nt], acc[nt], 0, 0, 0);
        #pragma unroll
        for (int nt = 0; nt < 4; ++nt) bcur[nt] = bnxt[nt];
    }

    // ---- epilogue2: relu(+b_out2), dot w_out3, reduce over 256 cols ----
    {
        float b2v[4], w3v[4];
        #pragma unroll
        for (int nt = 0; nt < 4; ++nt) {
            const int col = wbase + nt * 16 + m15;
            b2v[nt] = b_out2[col];
            w3v[nt] = w_out3[col];
        }
        #pragma unroll
        for (int reg = 0; reg < 4; ++reg) {
            float p = 0.f;
            #pragma unroll
            for (int nt = 0; nt < 4; ++nt)
                p += fmaxf(acc[nt][reg] + b2v[nt], 0.f) * w3v[nt];
            p += __shfl_xor(p, 1, 64);
            p += __shfl_xor(p, 2, 64);
            p += __shfl_xor(p, 4, 64);
            p += __shfl_xor(p, 8, 64);
            if (m15 == 0) red[w][q * 4 + reg] = p;
        }
    }
    __syncthreads();
    if (tid < 16) {
        const int R = R0 + tid;
        if (R < NROWS) {
            const float val = red[0][tid] + red[1][tid] + red[2][tid] + red[3][tid] + b_out3[0];
            const int b = R / (TM * NA), rem = R % (TM * NA);
            const int t = rem / NA, n = rem % NA;
            out[(b * NA + n) * TM + t] = val;
        }
    }
}

// ----------------------------------------------------------------
extern "C" void kernel_launch(void* const* d_in, const int* in_sizes, int n_in,
                              void* d_out, int out_size, void* d_ws, size_t ws_size,
                              hipStream_t stream) {
    const float* inputs  = (const float*)d_in[0];
    const float* mu      = (const float*)d_in[1];
    const float* logvar  = (const float*)d_in[2];
    const float* eps     = (const float*)d_in[3];
    const float* w_msg1  = (const float*)d_in[6];
    const float* b_msg1  = (const float*)d_in[7];
    const float* w_msg2  = (const float*)d_in[8];
    const float* b_msg2  = (const float*)d_in[9];
    const float* w_out1  = (const float*)d_in[10];
    const float* b_out1  = (const float*)d_in[11];
    const float* w_out2  = (const float*)d_in[12];
    const float* b_out2  = (const float*)d_in[13];
    const float* w_out3  = (const float*)d_in[14];
    const float* b_out3  = (const float*)d_in[15];
    float* out = (float*)d_out;

    // workspace (bf16 elems): u, v, agg (11700*256 each); frag-order W2, Wout1, Wout2
    bf16* u       = (bf16*)d_ws;
    bf16* v       = u       + NROWS * HID;
    bf16* aggw    = v       + NROWS * HID;
    bf16* w2frag  = aggw    + NROWS * HID;
    bf16* w1frag  = w2frag  + W2F_ELEMS;
    bf16* w2ofrag = w1frag  + W1F_ELEMS;   // total ~18.4 MB

    hipLaunchKernelGGL(k1_prep, dim3(UVB + 32 + 36 + 32), dim3(256), 0, stream,
                       inputs, w_msg1, b_msg1, w_msg2, w_out1, w_out2,
                       u, v, w2frag, w1frag, w2ofrag);
    hipLaunchKernelGGL(k2_msg, dim3(NB * NA * NTB), dim3(512), 0, stream,
                       u, v, w2frag, mu, logvar, eps, b_msg2, aggw);
    hipLaunchKernelGGL(k3_out, dim3((NROWS + 15) / 16), dim3(256), 0, stream,
                       aggw, inputs, w1frag, w2ofrag, b_out1, b_out2, w_out3, b_out3, out);
}

// Round 7
// 156.535 us; speedup vs baseline: 7.0344x; 1.0782x over previous
//
#include <hip/hip_runtime.h>

#define LAG 5
#define HID 256
#define NA 30
#define NE 870
#define TM 195
#define TT 200
#define NB 2
#define EPN 29
#define TB3 65                 // 195/3 time-tiles of 3
#define NROWS (NB * TM * NA)   // 11700 (b,t,n) rows
#define APAD 4
#define KC 32                  // K-chunk (1 MFMA k-step)
#define UVB 1463               // ceil(11700/8) u,v blocks in k1
#define W2F_ELEMS (HID * HID)  // 65536
#define W1F_ELEMS (HID * 288)  // 73728

typedef _Float16 f16;
typedef _Float16 f16x8 __attribute__((ext_vector_type(8)));
typedef float floatx4 __attribute__((ext_vector_type(4)));

// ---------------------------------------------------------------- K1: prep (f16 everywhere)
// [0,1463): u,v (8 rows/block) ; then W2 frag ; Wout1 frag ; Wout2 frag.
// Fragment order: chunk = col/16 ; element offset = ((chunk*KCHUNKS + kc)*64 + lane)*8.
// Lane holds B[col = chunk*16+(lane&15)][k = kc*32+(lane>>4)*8 .. +8] -> coalesced 16B/lane.
__global__ __launch_bounds__(256) void k1_prep(
    const float* __restrict__ inputs, const float* __restrict__ w_msg1,
    const float* __restrict__ b_msg1, const float* __restrict__ w_msg2,
    const float* __restrict__ w_out1, const float* __restrict__ w_out2,
    f16* __restrict__ u, f16* __restrict__ v, f16* __restrict__ w2frag,
    f16* __restrict__ w1frag, f16* __restrict__ w2ofrag)
{
    const int bid = blockIdx.x, tid = threadIdx.x;
    if (bid < UVB) {
        __shared__ float feats8[8][LAG];
        const int r0 = bid * 8;
        if (tid < 8 * LAG) {
            const int i = tid / LAG, l = tid % LAG;
            const int r = r0 + i;
            float fv = 0.f;
            if (r < NROWS) {
                const int b = r / (TM * NA), rem = r % (TM * NA);
                const int t = rem / NA, n = rem % NA;
                fv = inputs[(b * NA + n) * TT + t + l];
            }
            feats8[i][l] = fv;
        }
        float w1c[2 * LAG];
        #pragma unroll
        for (int k = 0; k < 2 * LAG; ++k) w1c[k] = w_msg1[k * HID + tid];
        const float bb = b_msg1[tid];
        __syncthreads();
        #pragma unroll
        for (int i = 0; i < 8; ++i) {
            const int r = r0 + i;
            if (r < NROWS) {
                float ua = bb, va = 0.f;
                #pragma unroll
                for (int l = 0; l < LAG; ++l) {
                    ua = fmaf(feats8[i][l], w1c[l], ua);
                    va = fmaf(feats8[i][l], w1c[LAG + l], va);
                }
                u[(r << 8) + tid] = (f16)ua;
                v[(r << 8) + tid] = (f16)va;
            }
        }
    } else if (bid < UVB + 32) {                      // W2^T frag (8 k-chunks)
        const int fidx = (bid - UVB) * 256 + tid;     // [0, 8192)
        const int lane = fidx & 63;
        const int kc = (fidx >> 6) & 7;
        const int ntc = fidx >> 9;                    // chunk = col/16
        const int col = ntc * 16 + (lane & 15);
        const int kb = kc * KC + (lane >> 4) * 8;
        f16x8 vv;
        #pragma unroll
        for (int x = 0; x < 8; ++x) vv[x] = (f16)w_msg2[(kb + x) * HID + col];
        *(f16x8*)&w2frag[fidx * 8] = vv;
    } else if (bid < UVB + 32 + 36) {                 // W_out1' frag (9 k-chunks, K=288)
        const int fidx = (bid - (UVB + 32)) * 256 + tid;  // [0, 9216)
        const int lane = fidx & 63;
        const int kc = (fidx >> 6) % 9;
        const int ntc = fidx / (64 * 9);
        const int col = ntc * 16 + (lane & 15);
        const int kb = kc * KC + (lane >> 4) * 8;
        f16x8 vv;
        #pragma unroll
        for (int x = 0; x < 8; ++x) {
            const int k = kb + x;
            float val;
            if (k < 256)      val = w_out1[(5 + k) * HID + col];   // agg part (rows 5..260)
            else if (k < 261) val = w_out1[(k - 256) * HID + col]; // feat part (rows 0..4)
            else              val = 0.f;                           // K-pad
            vv[x] = (f16)val;
        }
        *(f16x8*)&w1frag[fidx * 8] = vv;
    } else {                                          // W_out2^T frag (8 k-chunks)
        const int fidx = (bid - (UVB + 32 + 36)) * 256 + tid;
        const int lane = fidx & 63;
        const int kc = (fidx >> 6) & 7;
        const int ntc = fidx >> 9;
        const int col = ntc * 16 + (lane & 15);
        const int kb = kc * KC + (lane >> 4) * 8;
        f16x8 vv;
        #pragma unroll
        for (int x = 0; x < 8; ++x) vv[x] = (f16)w_msg2[0] * (f16)0.f + (f16)w_out2[(kb + x) * HID + col];
        *(f16x8*)&w2ofrag[fidx * 8] = vv;
    }
}

// ---------------------------------------------------------------- K2: msg MLP + edge-weighted aggregation
// 512 threads / 8 waves; block per (b, n, t-tile of 3). M=96 (3t x 32 edge-slots), N=256 (32/wave), K=256.
// B from frag-order global (coalesced), prefetch depth 2, one barrier total.
__global__ __launch_bounds__(512, 4) void k2_msg(
    const f16* __restrict__ u, const f16* __restrict__ v,
    const f16* __restrict__ w2frag,
    const float* __restrict__ mu, const float* __restrict__ logvar,
    const float* __restrict__ eps, const float* __restrict__ b_msg2,
    f16* __restrict__ agg)
{
    __shared__ f16 a_lds[96][HID + APAD];      // 49,920 B -> up to 3 blocks/CU
    __shared__ float ev_lds[32];

    const int bid = blockIdx.x;
    const int n  = bid % NA;
    const int tb = (bid / NA) % TB3;
    const int b  = bid / (NA * TB3);
    const int t0 = tb * 3;
    const int tid = threadIdx.x;
    const int lane = tid & 63, w = tid >> 6;   // w in [0,8)
    const int q = lane >> 4, m15 = lane & 15;
    const int wbase = w * 32;                  // 32-col slice per wave

    if (tid < 32) {
        float evv = 0.f;
        if (tid < EPN) {
            const int e = b * NE + n * EPN + tid;
            evv = eps[e] * __expf(0.5f * logvar[e]) + mu[e];
        }
        ev_lds[tid] = evv;
    }

    const f16x8 z8 = {(f16)0, (f16)0, (f16)0, (f16)0, (f16)0, (f16)0, (f16)0, (f16)0};

    // ---- stage A = relu(u[send] + v[recv]) : 96 rows x 32 chunks = 3072 tasks, packed f16 math ----
    #pragma unroll
    for (int i = 0; i < 6; ++i) {
        const int task = i * 512 + tid;
        const int row = task >> 5, c = task & 31;
        const int tt = row >> 5, ei = row & 31;
        f16x8 out8;
        if (ei < EPN) {
            const int t = t0 + tt;                       // always < TM (195 = 65*3)
            const int j = ei + (ei >= n);
            const f16x8 uu = *(const f16x8*)(u + ((((b * TM + t) * NA + j) << 8) + c * 8));
            const f16x8 vv = *(const f16x8*)(v + ((((b * TM + t) * NA + n) << 8) + c * 8));
            out8 = __builtin_elementwise_max(uu + vv, z8);   // v_pk_add_f16 + v_pk_max_f16
        } else {
            out8 = z8;                                   // zero pad rows
        }
        *(f16x8*)&a_lds[row][c * 8] = out8;
    }

    // frag-order B: chunk = col/16 = w*2+nt ; offset = ((chunk*8 + kc) << 9) + (lane << 3)
    const f16* bbase = w2frag + (lane << 3);
    f16x8 b0[2], b1[2], b2[2];
    #pragma unroll
    for (int nt = 0; nt < 2; ++nt) {
        b0[nt] = *(const f16x8*)(bbase + (((w * 2 + nt) * 8 + 0) << 9));
        b1[nt] = *(const f16x8*)(bbase + (((w * 2 + nt) * 8 + 1) << 9));
    }

    floatx4 acc[6][2];
    #pragma unroll
    for (int mt = 0; mt < 6; ++mt)
        #pragma unroll
        for (int nt = 0; nt < 2; ++nt)
            acc[mt][nt] = (floatx4){0.f, 0.f, 0.f, 0.f};

    __syncthreads();   // A staged (the only barrier)

    #pragma unroll
    for (int kc = 0; kc < 8; ++kc) {
        if (kc < 6) {
            #pragma unroll
            for (int nt = 0; nt < 2; ++nt)
                b2[nt] = *(const f16x8*)(bbase + (((w * 2 + nt) * 8 + kc + 2) << 9));
        }
        f16x8 af[6];
        #pragma unroll
        for (int mt = 0; mt < 6; ++mt)
            af[mt] = *(const f16x8*)&a_lds[mt * 16 + m15][kc * KC + q * 8];
        #pragma unroll
        for (int nt = 0; nt < 2; ++nt)
            #pragma unroll
            for (int mt = 0; mt < 6; ++mt)
                acc[mt][nt] = __builtin_amdgcn_mfma_f32_16x16x32_f16(af[mt], b0[nt], acc[mt][nt], 0, 0, 0);
        #pragma unroll
        for (int nt = 0; nt < 2; ++nt) { b0[nt] = b1[nt]; b1[nt] = b2[nt]; }
    }

    // ---- epilogue: msg = relu(acc + b2) * edgeval ; sum edges -> agg[b,t,n,:] ----
    float b2v[2];
    #pragma unroll
    for (int nt = 0; nt < 2; ++nt) b2v[nt] = b_msg2[wbase + nt * 16 + m15];

    #pragma unroll
    for (int tt = 0; tt < 3; ++tt) {
        const int t = t0 + tt;
        #pragma unroll
        for (int nt = 0; nt < 2; ++nt) {
            float part = 0.f;
            #pragma unroll
            for (int ml = 0; ml < 2; ++ml) {
                const int mt = tt * 2 + ml;
                #pragma unroll
                for (int reg = 0; reg < 4; ++reg) {
                    const int ei = (ml * 16 + q * 4 + reg);    // C-layout row = q*4+reg
                    part += ev_lds[ei] * fmaxf(acc[mt][nt][reg] + b2v[nt], 0.f);
                }
            }
            part += __shfl_xor(part, 16, 64);
            part += __shfl_xor(part, 32, 64);
            if (q == 0)
                agg[((((b * TM + t) * NA + n) << 8) + wbase + nt * 16 + m15)] = (f16)part;
        }
    }
}

// ---------------------------------------------------------------- K3: out MLP 288->256->256->1 (f16)
// block per 16 rows (732 blocks). B from frag-order global, double-buffered.
__global__ __launch_bounds__(256) void k3_out(
    const f16* __restrict__ agg, const float* __restrict__ inputs,
    const f16* __restrict__ w1frag, const f16* __restrict__ w2ofrag,
    const float* __restrict__ b_out1, const float* __restrict__ b_out2,
    const float* __restrict__ w_out3, const float* __restrict__ b_out3,
    float* __restrict__ out)
{
    __shared__ f16 a1[16][288 + APAD];
    __shared__ float red[4][16];

    const int R0 = blockIdx.x * 16;
    const int tid = threadIdx.x;
    const int lane = tid & 63, w = tid >> 6;
    const int q = lane >> 4, m15 = lane & 15;
    const int wbase = w * 64;

    // ---- stage A1 = [agg(256) | feat(5) | 0...] ----
    #pragma unroll
    for (int i = 0; i < 2; ++i) {
        const int task = i * 256 + tid;                // [0,512): 16 rows x 32 chunks
        const int row = task >> 5, c = task & 31;
        const int R = R0 + row;
        f16x8 val;
        if (R < NROWS) {
            val = *(const f16x8*)&agg[(R << 8) + c * 8];
        } else {
            for (int x = 0; x < 8; ++x) val[x] = (f16)0.f;
        }
        *(f16x8*)&a1[row][c * 8] = val;
    }
    if (tid < 16) {
        const int R = R0 + tid;
        if (R < NROWS) {
            const int b = R / (TM * NA), rem = R % (TM * NA);
            const int t = rem / NA, n = rem % NA;
            const float* ip = inputs + (b * NA + n) * TT + t;
            #pragma unroll
            for (int l = 0; l < LAG; ++l) a1[tid][256 + l] = (f16)ip[l];
            #pragma unroll
            for (int k = 261; k < 288; ++k) a1[tid][k] = (f16)0.f;
        } else {
            for (int k = 256; k < 288; ++k) a1[tid][k] = (f16)0.f;
        }
    }

    floatx4 acc[4];
    #pragma unroll
    for (int nt = 0; nt < 4; ++nt) acc[nt] = (floatx4){0.f, 0.f, 0.f, 0.f};

    // ---- GEMM1: K=288 (9 chunks) ----
    const f16* b1base = w1frag + (lane << 3);
    f16x8 bcur[4], bnxt[4];
    #pragma unroll
    for (int nt = 0; nt < 4; ++nt)
        bcur[nt] = *(const f16x8*)(b1base + (((w * 4 + nt) * 9 + 0) << 9));

    __syncthreads();   // A1 staged

    #pragma unroll
    for (int kc = 0; kc < 9; ++kc) {
        if (kc < 8) {
            #pragma unroll
            for (int nt = 0; nt < 4; ++nt)
                bnxt[nt] = *(const f16x8*)(b1base + (((w * 4 + nt) * 9 + kc + 1) << 9));
        }
        const f16x8 af = *(const f16x8*)&a1[m15][kc * KC + q * 8];
        #pragma unroll
        for (int nt = 0; nt < 4; ++nt)
            acc[nt] = __builtin_amdgcn_mfma_f32_16x16x32_f16(af, bcur[nt], acc[nt], 0, 0, 0);
        #pragma unroll
        for (int nt = 0; nt < 4; ++nt) bcur[nt] = bnxt[nt];
    }
    __syncthreads();   // all GEMM1 reads of a1 done before overwrite

    // ---- epilogue1: out1 = relu(acc + b_out1) -> a1[:, 0:256] ----
    {
        float b1v[4];
        #pragma unroll
        for (int nt = 0; nt < 4; ++nt) b1v[nt] = b_out1[wbase + nt * 16 + m15];
        #pragma unroll
        for (int nt = 0; nt < 4; ++nt)
            #pragma unroll
            for (int reg = 0; reg < 4; ++reg)
                a1[q * 4 + reg][wbase + nt * 16 + m15] =
                    (f16)fmaxf(acc[nt][reg] + b1v[nt], 0.f);
    }

    #pragma unroll
    for (int nt = 0; nt < 4; ++nt) acc[nt] = (floatx4){0.f, 0.f, 0.f, 0.f};

    // ---- GEMM2: K=256 (8 chunks) ----
    const f16* b2base = w2ofrag + (lane << 3);
    #pragma unroll
    for (int nt = 0; nt < 4; ++nt)
        bcur[nt] = *(const f16x8*)(b2base + (((w * 4 + nt) * 8 + 0) << 9));

    __syncthreads();   // epilogue1 writes visible

    #pragma unroll
    for (int kc = 0; kc < 8; ++kc) {
        if (kc < 7) {
            #pragma unroll
            for (int nt = 0; nt < 4; ++nt)
                bnxt[nt] = *(const f16x8*)(b2base + (((w * 4 + nt) * 8 + kc + 1) << 9));
        }
        const f16x8 af = *(const f16x8*)&a1[m15][kc * KC + q * 8];
        #pragma unroll
        for (int nt = 0; nt < 4; ++nt)
            acc[nt] = __builtin_amdgcn_mfma_f32_16x16x32_f16(af, bcur[nt], acc[nt], 0, 0, 0);
        #pragma unroll
        for (int nt = 0; nt < 4; ++nt) bcur[nt] = bnxt[nt];
    }

    // ---- epilogue2: relu(+b_out2), dot w_out3, reduce over 256 cols ----
    {
        float b2v[4], w3v[4];
        #pragma unroll
        for (int nt = 0; nt < 4; ++nt) {
            const int col = wbase + nt * 16 + m15;
            b2v[nt] = b_out2[col];
            w3v[nt] = w_out3[col];
        }
        #pragma unroll
        for (int reg = 0; reg < 4; ++reg) {
            float p = 0.f;
            #pragma unroll
            for (int nt = 0; nt < 4; ++nt)
                p += fmaxf(acc[nt][reg] + b2v[nt], 0.f) * w3v[nt];
            p += __shfl_xor(p, 1, 64);
            p += __shfl_xor(p, 2, 64);
            p += __shfl_xor(p, 4, 64);
            p += __shfl_xor(p, 8, 64);
            if (m15 == 0) red[w][q * 4 + reg] = p;
        }
    }
    __syncthreads();
    if (tid < 16) {
        const int R = R0 + tid;
        if (R < NROWS) {
            const float val = red[0][tid] + red[1][tid] + red[2][tid] + red[3][tid] + b_out3[0];
            const int b = R / (TM * NA), rem = R % (TM * NA);
            const int t = rem / NA, n = rem % NA;
            out[(b * NA + n) * TM + t] = val;
        }
    }
}

// ----------------------------------------------------------------
extern "C" void kernel_launch(void* const* d_in, const int* in_sizes, int n_in,
                              void* d_out, int out_size, void* d_ws, size_t ws_size,
                              hipStream_t stream) {
    const float* inputs  = (const float*)d_in[0];
    const float* mu      = (const float*)d_in[1];
    const float* logvar  = (const float*)d_in[2];
    const float* eps     = (const float*)d_in[3];
    const float* w_msg1  = (const float*)d_in[6];
    const float* b_msg1  = (const float*)d_in[7];
    const float* w_msg2  = (const float*)d_in[8];
    const float* b_msg2  = (const float*)d_in[9];
    const float* w_out1  = (const float*)d_in[10];
    const float* b_out1  = (const float*)d_in[11];
    const float* w_out2  = (const float*)d_in[12];
    const float* b_out2  = (const float*)d_in[13];
    const float* w_out3  = (const float*)d_in[14];
    const float* b_out3  = (const float*)d_in[15];
    float* out = (float*)d_out;

    // workspace (f16 elems): u, v, agg (11700*256 each); frag-order W2, Wout1, Wout2
    f16* u       = (f16*)d_ws;
    f16* v       = u       + NROWS * HID;
    f16* aggw    = v       + NROWS * HID;
    f16* w2frag  = aggw    + NROWS * HID;
    f16* w1frag  = w2frag  + W2F_ELEMS;
    f16* w2ofrag = w1frag  + W1F_ELEMS;   // total ~18.4 MB

    hipLaunchKernelGGL(k1_prep, dim3(UVB + 32 + 36 + 32), dim3(256), 0, stream,
                       inputs, w_msg1, b_msg1, w_msg2, w_out1, w_out2,
                       u, v, w2frag, w1frag, w2ofrag);
    hipLaunchKernelGGL(k2_msg, dim3(NB * NA * TB3), dim3(512), 0, stream,
                       u, v, w2frag, mu, logvar, eps, b_msg2, aggw);
    hipLaunchKernelGGL(k3_out, dim3((NROWS + 15) / 16), dim3(256), 0, stream,
                       aggw, inputs, w1frag, w2ofrag, b_out1, b_out2, w_out3, b_out3, out);
}